// Round 1
// baseline (2843.375 us; speedup 1.0000x reference)
//
#include <hip/hip_runtime.h>
#include <math.h>

#define N_NODES 50000
#define N_EDGES 400000
#define N_GRAPHS 512
#define NEG_SLOPE 0.2f
#define BN_EPS 1e-5f

// ---- float <-> orderable uint (for atomicMax on float incl. negatives) ----
__device__ __forceinline__ unsigned f2o(float f) {
    unsigned b = __float_as_uint(f);
    return (b & 0x80000000u) ? ~b : (b | 0x80000000u);
}
__device__ __forceinline__ float o2f(unsigned u) {
    return (u & 0x80000000u) ? __uint_as_float(u & 0x7fffffffu)
                             : __uint_as_float(~u);
}

// ---- fp32 GEMM: C[n x M] = A[n x K] * W[K x M], all row-major ----
// BM=64, BN=64, BK=16, 256 threads, 4x4 per thread.
__global__ __launch_bounds__(256) void gemm_kernel(
    const float* __restrict__ A, const float* __restrict__ W,
    float* __restrict__ C, int n, int K, int M) {
    __shared__ float As[16][68];  // [k][m], pad to 68 so float4 reads stay 16B-aligned
    __shared__ float Ws[16][64];  // [k][n]
    const int tid = threadIdx.x;
    const int tx = tid & 15, ty = tid >> 4;
    const int row0 = blockIdx.x * 64;
    const int col0 = blockIdx.y * 64;

    const int lm = tid >> 2;         // 0..63: row within A tile
    const int lk = (tid & 3) * 4;    // k quad within A tile
    const int wk = tid >> 4;         // 0..15: k for W load
    const int wn = (tid & 15) * 4;   // col quad for W load

    float c[4][4] = {};

    for (int k0 = 0; k0 < K; k0 += 16) {
        int arow = row0 + lm;
        float4 av = make_float4(0.f, 0.f, 0.f, 0.f);
        if (arow < n) av = *(const float4*)(A + (size_t)arow * K + k0 + lk);
        As[lk + 0][lm] = av.x;
        As[lk + 1][lm] = av.y;
        As[lk + 2][lm] = av.z;
        As[lk + 3][lm] = av.w;
        *(float4*)&Ws[wk][wn] = *(const float4*)(W + (size_t)(k0 + wk) * M + col0 + wn);
        __syncthreads();
#pragma unroll
        for (int kk = 0; kk < 16; ++kk) {
            float4 a4 = *(const float4*)&As[kk][ty * 4];
            float4 b4 = *(const float4*)&Ws[kk][tx * 4];
            float a[4] = {a4.x, a4.y, a4.z, a4.w};
            float b[4] = {b4.x, b4.y, b4.z, b4.w};
#pragma unroll
            for (int i = 0; i < 4; ++i)
#pragma unroll
                for (int j = 0; j < 4; ++j) c[i][j] += a[i] * b[j];
        }
        __syncthreads();
    }
#pragma unroll
    for (int i = 0; i < 4; ++i) {
        int r = row0 + ty * 4 + i;
        if (r < n) {
            float4 v = make_float4(c[i][0], c[i][1], c[i][2], c[i][3]);
            *(float4*)(C + (size_t)r * M + col0 + tx * 4) = v;
        }
    }
}

// ---- edge logits: e = att . leaky_relu(xl[src] + xr[dst]); atomicMax per dst ----
template <int FO, int VEC>
__global__ __launch_bounds__(256) void edge_logits_kernel(
    const int* __restrict__ ei, const float* __restrict__ xl,
    const float* __restrict__ xr, const float* __restrict__ att,
    float* __restrict__ ew, unsigned* __restrict__ emax) {
    const int e = blockIdx.x * 4 + (threadIdx.x >> 6);
    const int lane = threadIdx.x & 63;
    if (e >= N_EDGES) return;
    const int src = ei[e];
    const int dst = ei[N_EDGES + e];
    const float* pl = xl + (size_t)src * FO + lane * VEC;
    const float* pr = xr + (size_t)dst * FO + lane * VEC;
    const float* pa = att + lane * VEC;
    float acc = 0.f;
    if constexpr (VEC == 4) {
        float4 l = *(const float4*)pl, r = *(const float4*)pr, a = *(const float4*)pa;
        float z;
        z = l.x + r.x; z = z > 0.f ? z : NEG_SLOPE * z; acc += z * a.x;
        z = l.y + r.y; z = z > 0.f ? z : NEG_SLOPE * z; acc += z * a.y;
        z = l.z + r.z; z = z > 0.f ? z : NEG_SLOPE * z; acc += z * a.z;
        z = l.w + r.w; z = z > 0.f ? z : NEG_SLOPE * z; acc += z * a.w;
    } else {
        float2 l = *(const float2*)pl, r = *(const float2*)pr, a = *(const float2*)pa;
        float z;
        z = l.x + r.x; z = z > 0.f ? z : NEG_SLOPE * z; acc += z * a.x;
        z = l.y + r.y; z = z > 0.f ? z : NEG_SLOPE * z; acc += z * a.y;
    }
#pragma unroll
    for (int o = 32; o; o >>= 1) acc += __shfl_xor(acc, o, 64);
    if (lane == 0) {
        ew[e] = acc;
        atomicMax(emax + dst, f2o(acc));
    }
}

// ---- edge exp: ex = exp(e - max[dst]); atomicAdd per-dst sum ----
__global__ void edge_exp_kernel(const int* __restrict__ ei, float* __restrict__ ew,
                                const unsigned* __restrict__ emax,
                                float* __restrict__ esum) {
    const int e = blockIdx.x * 256 + threadIdx.x;
    if (e >= N_EDGES) return;
    const int dst = ei[N_EDGES + e];
    const float m = o2f(emax[dst]);
    const float ex = expf(ew[e] - m);
    ew[e] = ex;
    atomicAdd(esum + dst, ex);
}

// ---- edge aggregation: out[dst] += (ex/sum) * xl[src] ----
template <int FO, int VEC>
__global__ __launch_bounds__(256) void edge_agg_kernel(
    const int* __restrict__ ei, const float* __restrict__ xl,
    const float* __restrict__ ew, const float* __restrict__ esum,
    float* __restrict__ out) {
    const int e = blockIdx.x * 4 + (threadIdx.x >> 6);
    const int lane = threadIdx.x & 63;
    if (e >= N_EDGES) return;
    const int src = ei[e];
    const int dst = ei[N_EDGES + e];
    const float a = ew[e] / (esum[dst] + 1e-16f);
    const float* pl = xl + (size_t)src * FO + lane * VEC;
    float* po = out + (size_t)dst * FO + lane * VEC;
    if constexpr (VEC == 4) {
        float4 l = *(const float4*)pl;
        atomicAdd(po + 0, a * l.x);
        atomicAdd(po + 1, a * l.y);
        atomicAdd(po + 2, a * l.z);
        atomicAdd(po + 3, a * l.w);
    } else {
        float2 l = *(const float2*)pl;
        atomicAdd(po + 0, a * l.x);
        atomicAdd(po + 1, a * l.y);
    }
}

// ---- bias + optional relu ----
__global__ void bias_act_kernel(float* __restrict__ h, const float* __restrict__ b,
                                int total, int comask, int do_relu) {
    const int i = blockIdx.x * 256 + threadIdx.x;
    if (i >= total) return;
    float v = h[i] + b[i & comask];
    if (do_relu) v = fmaxf(v, 0.f);
    h[i] = v;
}

// ---- global mean pool (sum + count via atomics) ----
__global__ void pool_kernel(const float* __restrict__ h, const int* __restrict__ batch,
                            float* __restrict__ gsum, float* __restrict__ gcnt) {
    const int idx = blockIdx.x * 256 + threadIdx.x;
    if (idx >= N_NODES * 32) return;
    const int i = idx >> 5, q = idx & 31;
    const int b = batch[i];
    float4 v = *(const float4*)(h + (size_t)i * 128 + q * 4);
    atomicAdd(&gsum[b * 128 + q * 4 + 0], v.x);
    atomicAdd(&gsum[b * 128 + q * 4 + 1], v.y);
    atomicAdd(&gsum[b * 128 + q * 4 + 2], v.z);
    atomicAdd(&gsum[b * 128 + q * 4 + 3], v.w);
    if (q == 0) atomicAdd(&gcnt[b], 1.f);
}

// ---- fused MLP head: bng -> lin1+relu+bn1 -> lin2+relu+bn2 -> lin3+relu ----
__global__ __launch_bounds__(128) void mlp_kernel(
    const float* __restrict__ gsum, const float* __restrict__ gcnt,
    const float* __restrict__ W1, const float* __restrict__ b1,
    const float* __restrict__ W2, const float* __restrict__ b2,
    const float* __restrict__ W3, const float* __restrict__ b3,
    const float* __restrict__ bng_g, const float* __restrict__ bng_b,
    const float* __restrict__ bng_m, const float* __restrict__ bng_v,
    const float* __restrict__ bn1_g, const float* __restrict__ bn1_b,
    const float* __restrict__ bn1_m, const float* __restrict__ bn1_v,
    const float* __restrict__ bn2_g, const float* __restrict__ bn2_b,
    const float* __restrict__ bn2_m, const float* __restrict__ bn2_v,
    float* __restrict__ out) {
    __shared__ float s0[128], s1[128], s2[64];
    const int g = blockIdx.x, t = threadIdx.x;
    const float cnt = fmaxf(gcnt[g], 1.f);
    float v = gsum[g * 128 + t] / cnt;
    v = (v - bng_m[t]) * rsqrtf(bng_v[t] + BN_EPS) * bng_g[t] + bng_b[t];
    s0[t] = v;
    __syncthreads();
    float a1 = b1[t];
    for (int i = 0; i < 128; ++i) a1 += s0[i] * W1[i * 128 + t];
    a1 = fmaxf(a1, 0.f);
    a1 = (a1 - bn1_m[t]) * rsqrtf(bn1_v[t] + BN_EPS) * bn1_g[t] + bn1_b[t];
    s1[t] = a1;
    __syncthreads();
    if (t < 64) {
        float a2 = b2[t];
        for (int i = 0; i < 128; ++i) a2 += s1[i] * W2[i * 64 + t];
        a2 = fmaxf(a2, 0.f);
        a2 = (a2 - bn2_m[t]) * rsqrtf(bn2_v[t] + BN_EPS) * bn2_g[t] + bn2_b[t];
        s2[t] = a2;
    }
    __syncthreads();
    if (t < 2) {
        float a3 = b3[t];
        for (int i = 0; i < 64; ++i) a3 += s2[i] * W3[i * 2 + t];
        out[g * 2 + t] = fmaxf(a3, 0.f);
    }
}

extern "C" void kernel_launch(void* const* d_in, const int* in_sizes, int n_in,
                              void* d_out, int out_size, void* d_ws, size_t ws_size,
                              hipStream_t stream) {
    const float* x = (const float*)d_in[0];
    const int* ei = (const int*)d_in[1];
    const int* batch = (const int*)d_in[2];
    const float* Wl1 = (const float*)d_in[3];
    const float* Wr1 = (const float*)d_in[4];
    const float* att1 = (const float*)d_in[5];
    const float* b1 = (const float*)d_in[6];
    const float* Wl2 = (const float*)d_in[7];
    const float* Wr2 = (const float*)d_in[8];
    const float* att2 = (const float*)d_in[9];
    const float* b2 = (const float*)d_in[10];
    const float* Wl3 = (const float*)d_in[11];
    const float* Wr3 = (const float*)d_in[12];
    const float* att3 = (const float*)d_in[13];
    const float* b3 = (const float*)d_in[14];
    const float* Wlin1 = (const float*)d_in[15];
    const float* blin1 = (const float*)d_in[16];
    const float* Wlin2 = (const float*)d_in[17];
    const float* blin2 = (const float*)d_in[18];
    const float* Wlin3 = (const float*)d_in[19];
    const float* blin3 = (const float*)d_in[20];
    const float* bng_g = (const float*)d_in[21];
    const float* bng_b = (const float*)d_in[22];
    const float* bng_m = (const float*)d_in[23];
    const float* bng_v = (const float*)d_in[24];
    const float* bn1_g = (const float*)d_in[25];
    const float* bn1_b = (const float*)d_in[26];
    const float* bn1_m = (const float*)d_in[27];
    const float* bn1_v = (const float*)d_in[28];
    const float* bn2_g = (const float*)d_in[29];
    const float* bn2_b = (const float*)d_in[30];
    const float* bn2_m = (const float*)d_in[31];
    const float* bn2_v = (const float*)d_in[32];

    float* ws = (float*)d_ws;
    float* slot0 = ws;                                  // N*256
    float* slot1 = slot0 + (size_t)N_NODES * 256;       // N*256
    float* slot2 = slot1 + (size_t)N_NODES * 256;       // N*256
    float* ew = slot2 + (size_t)N_NODES * 256;          // E
    unsigned* emax = (unsigned*)(ew + N_EDGES);         // N
    float* esum = (float*)(emax + N_NODES);             // N
    float* gsum = esum + N_NODES;                       // G*128
    float* gcnt = gsum + (size_t)N_GRAPHS * 128;        // G

    const int eb = (N_EDGES + 3) / 4;

    auto layer = [&](const float* hin, int K, int FO, const float* Wl, const float* Wr,
                     const float* att, const float* bias, float* xl, float* xr,
                     float* agg, int do_relu) {
        dim3 gg((N_NODES + 63) / 64, FO / 64);
        gemm_kernel<<<gg, 256, 0, stream>>>(hin, Wl, xl, N_NODES, K, FO);
        gemm_kernel<<<gg, 256, 0, stream>>>(hin, Wr, xr, N_NODES, K, FO);
        hipMemsetAsync(emax, 0, N_NODES * 4, stream);   // 0 == orderable(-inf-ish)
        hipMemsetAsync(esum, 0, N_NODES * 4, stream);
        if (FO == 128)
            edge_logits_kernel<128, 2><<<eb, 256, 0, stream>>>(ei, xl, xr, att, ew, emax);
        else
            edge_logits_kernel<256, 4><<<eb, 256, 0, stream>>>(ei, xl, xr, att, ew, emax);
        edge_exp_kernel<<<(N_EDGES + 255) / 256, 256, 0, stream>>>(ei, ew, emax, esum);
        hipMemsetAsync(agg, 0, (size_t)N_NODES * FO * 4, stream);  // agg may alias xr
        if (FO == 128)
            edge_agg_kernel<128, 2><<<eb, 256, 0, stream>>>(ei, xl, ew, esum, agg);
        else
            edge_agg_kernel<256, 4><<<eb, 256, 0, stream>>>(ei, xl, ew, esum, agg);
        const int total = N_NODES * FO;
        bias_act_kernel<<<(total + 255) / 256, 256, 0, stream>>>(agg, bias, total,
                                                                 FO - 1, do_relu);
    };

    // L1: in=x(128) -> h1 in slot1 (128 cols)
    layer(x, 128, 128, Wl1, Wr1, att1, b1, slot0, slot1, slot1, 1);
    // L2: in=slot1(128) -> h2 in slot2 (256 cols)
    layer(slot1, 128, 256, Wl2, Wr2, att2, b2, slot0, slot2, slot2, 1);
    // L3: in=slot2(256) -> h3 in slot1 (128 cols), no relu
    layer(slot2, 256, 128, Wl3, Wr3, att3, b3, slot0, slot1, slot1, 0);

    // pool
    hipMemsetAsync(gsum, 0, (size_t)(N_GRAPHS * 128 + N_GRAPHS) * 4, stream);
    pool_kernel<<<(N_NODES * 32 + 255) / 256, 256, 0, stream>>>(slot1, batch, gsum, gcnt);

    // MLP head
    mlp_kernel<<<N_GRAPHS, 128, 0, stream>>>(
        gsum, gcnt, Wlin1, blin1, Wlin2, blin2, Wlin3, blin3,
        bng_g, bng_b, bng_m, bng_v, bn1_g, bn1_b, bn1_m, bn1_v,
        bn2_g, bn2_b, bn2_m, bn2_v, (float*)d_out);
}

// Round 2
// 769.060 us; speedup vs baseline: 3.6972x; 3.6972x over previous
//
#include <hip/hip_runtime.h>
#include <math.h>

#define N_NODES 50000
#define N_EDGES 400000
#define N_GRAPHS 512
#define NEG_SLOPE 0.2f
#define BN_EPS 1e-5f

// ---- fp32 GEMM: C[n x M] = A[n x K] * W[K x M], all row-major ----
// BM=64, BN=64, BK=16, 256 threads, 4x4 per thread.
__global__ __launch_bounds__(256) void gemm_kernel(
    const float* __restrict__ A, const float* __restrict__ W,
    float* __restrict__ C, int n, int K, int M) {
    __shared__ float As[16][68];  // [k][m], pad to 68 so float4 reads stay 16B-aligned
    __shared__ float Ws[16][64];  // [k][n]
    const int tid = threadIdx.x;
    const int tx = tid & 15, ty = tid >> 4;
    const int row0 = blockIdx.x * 64;
    const int col0 = blockIdx.y * 64;

    const int lm = tid >> 2;         // 0..63: row within A tile
    const int lk = (tid & 3) * 4;    // k quad within A tile
    const int wk = tid >> 4;         // 0..15: k for W load
    const int wn = (tid & 15) * 4;   // col quad for W load

    float c[4][4] = {};

    for (int k0 = 0; k0 < K; k0 += 16) {
        int arow = row0 + lm;
        float4 av = make_float4(0.f, 0.f, 0.f, 0.f);
        if (arow < n) av = *(const float4*)(A + (size_t)arow * K + k0 + lk);
        As[lk + 0][lm] = av.x;
        As[lk + 1][lm] = av.y;
        As[lk + 2][lm] = av.z;
        As[lk + 3][lm] = av.w;
        *(float4*)&Ws[wk][wn] = *(const float4*)(W + (size_t)(k0 + wk) * M + col0 + wn);
        __syncthreads();
#pragma unroll
        for (int kk = 0; kk < 16; ++kk) {
            float4 a4 = *(const float4*)&As[kk][ty * 4];
            float4 b4 = *(const float4*)&Ws[kk][tx * 4];
            float a[4] = {a4.x, a4.y, a4.z, a4.w};
            float b[4] = {b4.x, b4.y, b4.z, b4.w};
#pragma unroll
            for (int i = 0; i < 4; ++i)
#pragma unroll
                for (int j = 0; j < 4; ++j) c[i][j] += a[i] * b[j];
        }
        __syncthreads();
    }
#pragma unroll
    for (int i = 0; i < 4; ++i) {
        int r = row0 + ty * 4 + i;
        if (r < n) {
            float4 v = make_float4(c[i][0], c[i][1], c[i][2], c[i][3]);
            *(float4*)(C + (size_t)r * M + col0 + tx * 4) = v;
        }
    }
}

// ---- CSR build: deg count -> prefix scan -> fill src lists ----
__global__ void deg_count_kernel(const int* __restrict__ ei, int* __restrict__ deg) {
    const int e = blockIdx.x * 256 + threadIdx.x;
    if (e < N_EDGES) atomicAdd(&deg[ei[N_EDGES + e]], 1);
}

__global__ __launch_bounds__(1024) void scan_kernel(const int* __restrict__ deg,
                                                    int* __restrict__ rowp) {
    __shared__ int sdata[1024];
    const int t = threadIdx.x;
    const int CH = (N_NODES + 1023) / 1024;  // 49
    const int start = t * CH;
    const int end = min(start + CH, N_NODES);
    int sum = 0;
    for (int i = start; i < end; ++i) sum += deg[i];
    sdata[t] = sum;
    __syncthreads();
    for (int off = 1; off < 1024; off <<= 1) {
        int v = (t >= off) ? sdata[t - off] : 0;
        __syncthreads();
        sdata[t] += v;
        __syncthreads();
    }
    int excl = (t == 0) ? 0 : sdata[t - 1];
    for (int i = start; i < end; ++i) { rowp[i] = excl; excl += deg[i]; }
    if (t == 0) rowp[N_NODES] = N_EDGES;
}

__global__ void csr_fill_kernel(const int* __restrict__ ei, const int* __restrict__ rowp,
                                int* __restrict__ cursor, int* __restrict__ csr_src) {
    const int e = blockIdx.x * 256 + threadIdx.x;
    if (e >= N_EDGES) return;
    const int d = ei[N_EDGES + e];
    const int pos = atomicAdd(&cursor[d], 1);
    csr_src[rowp[d] + pos] = ei[e];
}

// ---- fused GATv2 edge phase: per-dst wave, online softmax, gather-only ----
// One wave (64 lanes) per dst node; lane holds features [lane*VEC, lane*VEC+VEC).
template <int FO, int VEC>
__global__ __launch_bounds__(256) void gat_edge_kernel(
    const int* __restrict__ rowp, const int* __restrict__ csr_src,
    const float* __restrict__ xl, const float* __restrict__ xr,
    const float* __restrict__ att, const float* __restrict__ bias,
    float* __restrict__ out, int do_relu) {
    const int d = blockIdx.x * 4 + (threadIdx.x >> 6);
    const int lane = threadIdx.x & 63;
    if (d >= N_NODES) return;
    const int co = lane * VEC;

    float a[VEC], r[VEC], acc[VEC];
    if constexpr (VEC == 4) {
        float4 t4 = *(const float4*)(att + co);
        a[0] = t4.x; a[1] = t4.y; a[2] = t4.z; a[3] = t4.w;
        t4 = *(const float4*)(xr + (size_t)d * FO + co);
        r[0] = t4.x; r[1] = t4.y; r[2] = t4.z; r[3] = t4.w;
    } else {
        float2 t2 = *(const float2*)(att + co);
        a[0] = t2.x; a[1] = t2.y;
        t2 = *(const float2*)(xr + (size_t)d * FO + co);
        r[0] = t2.x; r[1] = t2.y;
    }
#pragma unroll
    for (int k = 0; k < VEC; ++k) acc[k] = 0.f;

    const int jb = rowp[d], je = rowp[d + 1];
    float m = -INFINITY, s = 0.f;
    for (int j = jb; j < je; ++j) {
        const int src = csr_src[j];
        float l[VEC];
        if constexpr (VEC == 4) {
            float4 t4 = *(const float4*)(xl + (size_t)src * FO + co);
            l[0] = t4.x; l[1] = t4.y; l[2] = t4.z; l[3] = t4.w;
        } else {
            float2 t2 = *(const float2*)(xl + (size_t)src * FO + co);
            l[0] = t2.x; l[1] = t2.y;
        }
        float p = 0.f;
#pragma unroll
        for (int k = 0; k < VEC; ++k) {
            float z = l[k] + r[k];
            z = z > 0.f ? z : NEG_SLOPE * z;
            p += z * a[k];
        }
#pragma unroll
        for (int o = 32; o; o >>= 1) p += __shfl_xor(p, o, 64);
        const float mn = fmaxf(m, p);
        const float sc = __expf(m - mn);   // exp(-inf)=0 handles first edge
        const float w = __expf(p - mn);
        s = s * sc + w;
#pragma unroll
        for (int k = 0; k < VEC; ++k) acc[k] = acc[k] * sc + w * l[k];
        m = mn;
    }
    const float inv = 1.f / (s + 1e-16f);
#pragma unroll
    for (int k = 0; k < VEC; ++k) {
        float v = acc[k] * inv + bias[co + k];
        if (do_relu) v = fmaxf(v, 0.f);
        acc[k] = v;
    }
    if constexpr (VEC == 4) {
        *(float4*)(out + (size_t)d * FO + co) = make_float4(acc[0], acc[1], acc[2], acc[3]);
    } else {
        *(float2*)(out + (size_t)d * FO + co) = make_float2(acc[0], acc[1]);
    }
}

// ---- global mean pool (sum + count via atomics) ----
__global__ void pool_kernel(const float* __restrict__ h, const int* __restrict__ batch,
                            float* __restrict__ gsum, float* __restrict__ gcnt) {
    const int idx = blockIdx.x * 256 + threadIdx.x;
    if (idx >= N_NODES * 32) return;
    const int i = idx >> 5, q = idx & 31;
    const int b = batch[i];
    float4 v = *(const float4*)(h + (size_t)i * 128 + q * 4);
    atomicAdd(&gsum[b * 128 + q * 4 + 0], v.x);
    atomicAdd(&gsum[b * 128 + q * 4 + 1], v.y);
    atomicAdd(&gsum[b * 128 + q * 4 + 2], v.z);
    atomicAdd(&gsum[b * 128 + q * 4 + 3], v.w);
    if (q == 0) atomicAdd(&gcnt[b], 1.f);
}

// ---- fused MLP head: bng -> lin1+relu+bn1 -> lin2+relu+bn2 -> lin3+relu ----
__global__ __launch_bounds__(128) void mlp_kernel(
    const float* __restrict__ gsum, const float* __restrict__ gcnt,
    const float* __restrict__ W1, const float* __restrict__ b1,
    const float* __restrict__ W2, const float* __restrict__ b2,
    const float* __restrict__ W3, const float* __restrict__ b3,
    const float* __restrict__ bng_g, const float* __restrict__ bng_b,
    const float* __restrict__ bng_m, const float* __restrict__ bng_v,
    const float* __restrict__ bn1_g, const float* __restrict__ bn1_b,
    const float* __restrict__ bn1_m, const float* __restrict__ bn1_v,
    const float* __restrict__ bn2_g, const float* __restrict__ bn2_b,
    const float* __restrict__ bn2_m, const float* __restrict__ bn2_v,
    float* __restrict__ out) {
    __shared__ float s0[128], s1[128], s2[64];
    const int g = blockIdx.x, t = threadIdx.x;
    const float cnt = fmaxf(gcnt[g], 1.f);
    float v = gsum[g * 128 + t] / cnt;
    v = (v - bng_m[t]) * rsqrtf(bng_v[t] + BN_EPS) * bng_g[t] + bng_b[t];
    s0[t] = v;
    __syncthreads();
    float a1 = b1[t];
    for (int i = 0; i < 128; ++i) a1 += s0[i] * W1[i * 128 + t];
    a1 = fmaxf(a1, 0.f);
    a1 = (a1 - bn1_m[t]) * rsqrtf(bn1_v[t] + BN_EPS) * bn1_g[t] + bn1_b[t];
    s1[t] = a1;
    __syncthreads();
    if (t < 64) {
        float a2 = b2[t];
        for (int i = 0; i < 128; ++i) a2 += s1[i] * W2[i * 64 + t];
        a2 = fmaxf(a2, 0.f);
        a2 = (a2 - bn2_m[t]) * rsqrtf(bn2_v[t] + BN_EPS) * bn2_g[t] + bn2_b[t];
        s2[t] = a2;
    }
    __syncthreads();
    if (t < 2) {
        float a3 = b3[t];
        for (int i = 0; i < 64; ++i) a3 += s2[i] * W3[i * 2 + t];
        out[g * 2 + t] = fmaxf(a3, 0.f);
    }
}

extern "C" void kernel_launch(void* const* d_in, const int* in_sizes, int n_in,
                              void* d_out, int out_size, void* d_ws, size_t ws_size,
                              hipStream_t stream) {
    const float* x = (const float*)d_in[0];
    const int* ei = (const int*)d_in[1];
    const int* batch = (const int*)d_in[2];
    const float* Wl1 = (const float*)d_in[3];
    const float* Wr1 = (const float*)d_in[4];
    const float* att1 = (const float*)d_in[5];
    const float* b1 = (const float*)d_in[6];
    const float* Wl2 = (const float*)d_in[7];
    const float* Wr2 = (const float*)d_in[8];
    const float* att2 = (const float*)d_in[9];
    const float* b2 = (const float*)d_in[10];
    const float* Wl3 = (const float*)d_in[11];
    const float* Wr3 = (const float*)d_in[12];
    const float* att3 = (const float*)d_in[13];
    const float* b3 = (const float*)d_in[14];
    const float* Wlin1 = (const float*)d_in[15];
    const float* blin1 = (const float*)d_in[16];
    const float* Wlin2 = (const float*)d_in[17];
    const float* blin2 = (const float*)d_in[18];
    const float* Wlin3 = (const float*)d_in[19];
    const float* blin3 = (const float*)d_in[20];
    const float* bng_g = (const float*)d_in[21];
    const float* bng_b = (const float*)d_in[22];
    const float* bng_m = (const float*)d_in[23];
    const float* bng_v = (const float*)d_in[24];
    const float* bn1_g = (const float*)d_in[25];
    const float* bn1_b = (const float*)d_in[26];
    const float* bn1_m = (const float*)d_in[27];
    const float* bn1_v = (const float*)d_in[28];
    const float* bn2_g = (const float*)d_in[29];
    const float* bn2_b = (const float*)d_in[30];
    const float* bn2_m = (const float*)d_in[31];
    const float* bn2_v = (const float*)d_in[32];

    float* ws = (float*)d_ws;
    float* slot0 = ws;                                  // N*256 (xl)
    float* slot1 = slot0 + (size_t)N_NODES * 256;       // N*256 (xr)
    float* slot2 = slot1 + (size_t)N_NODES * 256;       // N*256 (h between layers)
    int* deg = (int*)(slot2 + (size_t)N_NODES * 256);   // N
    int* cursor = deg + N_NODES;                        // N
    int* rowp = cursor + N_NODES;                       // N+1
    int* csr_src = rowp + N_NODES + 1;                  // E
    float* gsum = (float*)(csr_src + N_EDGES);          // G*128
    float* gcnt = gsum + (size_t)N_GRAPHS * 128;        // G

    // ---- CSR build (graph is shared by all 3 layers) ----
    hipMemsetAsync(deg, 0, N_NODES * 4, stream);
    hipMemsetAsync(cursor, 0, N_NODES * 4, stream);
    const int eb = (N_EDGES + 255) / 256;
    deg_count_kernel<<<eb, 256, 0, stream>>>(ei, deg);
    scan_kernel<<<1, 1024, 0, stream>>>(deg, rowp);
    csr_fill_kernel<<<eb, 256, 0, stream>>>(ei, rowp, cursor, csr_src);

    const int nb = (N_NODES + 3) / 4;

    auto layer = [&](const float* hin, int K, int FO, const float* Wl, const float* Wr,
                     const float* att, const float* bias, float* hout, int do_relu) {
        dim3 gg((N_NODES + 63) / 64, FO / 64);
        gemm_kernel<<<gg, 256, 0, stream>>>(hin, Wl, slot0, N_NODES, K, FO);
        gemm_kernel<<<gg, 256, 0, stream>>>(hin, Wr, slot1, N_NODES, K, FO);
        if (FO == 128)
            gat_edge_kernel<128, 2><<<nb, 256, 0, stream>>>(rowp, csr_src, slot0, slot1,
                                                            att, bias, hout, do_relu);
        else
            gat_edge_kernel<256, 4><<<nb, 256, 0, stream>>>(rowp, csr_src, slot0, slot1,
                                                            att, bias, hout, do_relu);
    };

    // L1: in=x(128) -> h1 in slot2 (128 cols)
    layer(x, 128, 128, Wl1, Wr1, att1, b1, slot2, 1);
    // L2: in=slot2(128) -> h2 back into slot2 (256 cols; GEMMs read it first)
    layer(slot2, 128, 256, Wl2, Wr2, att2, b2, slot2, 1);
    // L3: in=slot2(256) -> h3 back into slot2 (128 cols), no relu
    layer(slot2, 256, 128, Wl3, Wr3, att3, b3, slot2, 0);

    // pool
    hipMemsetAsync(gsum, 0, (size_t)(N_GRAPHS * 128 + N_GRAPHS) * 4, stream);
    pool_kernel<<<(N_NODES * 32 + 255) / 256, 256, 0, stream>>>(slot2, batch, gsum, gcnt);

    // MLP head
    mlp_kernel<<<N_GRAPHS, 128, 0, stream>>>(
        gsum, gcnt, Wlin1, blin1, Wlin2, blin2, Wlin3, blin3,
        bng_g, bng_b, bng_m, bng_v, bn1_g, bn1_b, bn1_m, bn1_v,
        bn2_g, bn2_b, bn2_m, bn2_v, (float*)d_out);
}

// Round 3
// 494.641 us; speedup vs baseline: 5.7484x; 1.5548x over previous
//
#include <hip/hip_runtime.h>
#include <math.h>

#define N_NODES 50000
#define N_EDGES 400000
#define N_GRAPHS 512
#define NEG_SLOPE 0.2f
#define BN_EPS 1e-5f

typedef __attribute__((ext_vector_type(8))) short bf16x8;
typedef __attribute__((ext_vector_type(4))) float f32x4;

// ---- fp32 -> bf16 (round-to-nearest-even) ----
__device__ __forceinline__ ushort f2b(float f) {
    unsigned u = __float_as_uint(f);
    unsigned r = (u + 0x7fffu + ((u >> 16) & 1u)) >> 16;
    return (ushort)r;
}

// ---- activation fp32 -> bf16, vectorized x4 ----
__global__ void cvt_kernel(const float* __restrict__ in, ushort* __restrict__ out,
                           int total4) {
    const int i = blockIdx.x * 256 + threadIdx.x;
    if (i >= total4) return;
    float4 v = *(const float4*)(in + (size_t)i * 4);
    ushort4 o;
    o.x = f2b(v.x); o.y = f2b(v.y); o.z = f2b(v.z); o.w = f2b(v.w);
    *(ushort4*)(out + (size_t)i * 4) = o;
}

// ---- weight convert + transpose: W[K][M] fp32 -> Wt[M][K] bf16 ----
// ms = log2(M)
__global__ void wcvt_kernel(const float* __restrict__ W, ushort* __restrict__ Wt,
                            int K, int ms) {
    const int i = blockIdx.x * 256 + threadIdx.x;
    const int M = 1 << ms;
    if (i >= K * M) return;
    const int k = i >> ms, m = i & (M - 1);
    Wt[(size_t)m * K + k] = f2b(W[i]);
}

// ---- bf16 MFMA GEMM: C[n x M] = A[n x K] * B[K x M], A bf16 [n][K],
// Bt bf16 [M][K] (pre-transposed weight), C fp32 [n][M].
// Block tile 128x64, 4 waves (wave tile 64x32), BK=32.
__global__ __launch_bounds__(256) void gemm_bf16_kernel(
    const ushort* __restrict__ A, const ushort* __restrict__ Bt,
    float* __restrict__ C, int n, int K, int M) {
    __shared__ ushort As[128][40];  // pad to 40 shorts (80B): 2-way LDS conflict = free
    __shared__ ushort Bs[64][40];
    const int tid = threadIdx.x;
    const int row0 = blockIdx.x * 128;
    const int col0 = blockIdx.y * 64;
    const int w = tid >> 6, lane = tid & 63;
    const int wr = (w >> 1) * 64, wc = (w & 1) * 32;
    const int lr = lane & 15, kg = lane >> 4;

    const int arow = tid >> 1, ahalf = tid & 1;          // A: 128 rows x 2 x 32B
    const int brow = (tid & 127) >> 1, bhalf = tid & 1;  // B: 64 rows x 2 x 32B

    f32x4 acc[4][2];
#pragma unroll
    for (int i = 0; i < 4; ++i)
#pragma unroll
        for (int j = 0; j < 2; ++j) acc[i][j] = (f32x4){0.f, 0.f, 0.f, 0.f};

    for (int k0 = 0; k0 < K; k0 += 32) {
        {
            const int gr = row0 + arow;
            uint4 v0 = make_uint4(0, 0, 0, 0), v1 = v0;
            if (gr < n) {
                const uint4* p = (const uint4*)(A + (size_t)gr * K + k0) + ahalf * 2;
                v0 = p[0]; v1 = p[1];
            }
            uint4* d = (uint4*)&As[arow][ahalf * 16];
            d[0] = v0; d[1] = v1;
            if (tid < 128) {
                const int gb = col0 + brow;
                const uint4* p = (const uint4*)(Bt + (size_t)gb * K + k0) + bhalf * 2;
                uint4* db = (uint4*)&Bs[brow][bhalf * 16];
                db[0] = p[0]; db[1] = p[1];
            }
        }
        __syncthreads();
        bf16x8 af[4], bfr[2];
#pragma unroll
        for (int mi = 0; mi < 4; ++mi)
            af[mi] = *(const bf16x8*)&As[wr + mi * 16 + lr][kg * 8];
#pragma unroll
        for (int ni = 0; ni < 2; ++ni)
            bfr[ni] = *(const bf16x8*)&Bs[wc + ni * 16 + lr][kg * 8];
#pragma unroll
        for (int mi = 0; mi < 4; ++mi)
#pragma unroll
            for (int ni = 0; ni < 2; ++ni)
                acc[mi][ni] = __builtin_amdgcn_mfma_f32_16x16x32_bf16(
                    af[mi], bfr[ni], acc[mi][ni], 0, 0, 0);
        __syncthreads();
    }
#pragma unroll
    for (int mi = 0; mi < 4; ++mi)
#pragma unroll
        for (int ni = 0; ni < 2; ++ni)
#pragma unroll
            for (int j = 0; j < 4; ++j) {
                const int r = row0 + wr + mi * 16 + kg * 4 + j;
                if (r < n) C[(size_t)r * M + col0 + wc + ni * 16 + lr] = acc[mi][ni][j];
            }
}

// ---- CSR build ----
__global__ void deg_count_kernel(const int* __restrict__ ei, int* __restrict__ deg) {
    const int e = blockIdx.x * 256 + threadIdx.x;
    if (e < N_EDGES) atomicAdd(&deg[ei[N_EDGES + e]], 1);
}

__global__ __launch_bounds__(1024) void scan_kernel(const int* __restrict__ deg,
                                                    int* __restrict__ rowp) {
    __shared__ int sdata[1024];
    const int t = threadIdx.x;
    const int CH = (N_NODES + 1023) / 1024;
    const int start = t * CH;
    const int end = min(start + CH, N_NODES);
    int sum = 0;
    for (int i = start; i < end; ++i) sum += deg[i];
    sdata[t] = sum;
    __syncthreads();
    for (int off = 1; off < 1024; off <<= 1) {
        int v = (t >= off) ? sdata[t - off] : 0;
        __syncthreads();
        sdata[t] += v;
        __syncthreads();
    }
    int excl = (t == 0) ? 0 : sdata[t - 1];
    for (int i = start; i < end; ++i) { rowp[i] = excl; excl += deg[i]; }
    if (t == 0) rowp[N_NODES] = N_EDGES;
}

__global__ void csr_fill_kernel(const int* __restrict__ ei, const int* __restrict__ rowp,
                                int* __restrict__ cursor, int* __restrict__ csr_src) {
    const int e = blockIdx.x * 256 + threadIdx.x;
    if (e >= N_EDGES) return;
    const int d = ei[N_EDGES + e];
    const int pos = atomicAdd(&cursor[d], 1);
    csr_src[rowp[d] + pos] = ei[e];
}

// ---- fused GATv2 edge phase: per-dst wave, online softmax, gather-only ----
template <int FO, int VEC>
__global__ __launch_bounds__(256) void gat_edge_kernel(
    const int* __restrict__ rowp, const int* __restrict__ csr_src,
    const float* __restrict__ xl, const float* __restrict__ xr,
    const float* __restrict__ att, const float* __restrict__ bias,
    float* __restrict__ outf, ushort* __restrict__ outb, int do_relu) {
    const int d = blockIdx.x * 4 + (threadIdx.x >> 6);
    const int lane = threadIdx.x & 63;
    if (d >= N_NODES) return;
    const int co = lane * VEC;

    float a[VEC], r[VEC], acc[VEC];
    if constexpr (VEC == 4) {
        float4 t4 = *(const float4*)(att + co);
        a[0] = t4.x; a[1] = t4.y; a[2] = t4.z; a[3] = t4.w;
        t4 = *(const float4*)(xr + (size_t)d * FO + co);
        r[0] = t4.x; r[1] = t4.y; r[2] = t4.z; r[3] = t4.w;
    } else {
        float2 t2 = *(const float2*)(att + co);
        a[0] = t2.x; a[1] = t2.y;
        t2 = *(const float2*)(xr + (size_t)d * FO + co);
        r[0] = t2.x; r[1] = t2.y;
    }
#pragma unroll
    for (int k = 0; k < VEC; ++k) acc[k] = 0.f;

    const int jb = rowp[d], je = rowp[d + 1];
    float m = -INFINITY, s = 0.f;
    for (int j = jb; j < je; ++j) {
        const int src = csr_src[j];
        float l[VEC];
        if constexpr (VEC == 4) {
            float4 t4 = *(const float4*)(xl + (size_t)src * FO + co);
            l[0] = t4.x; l[1] = t4.y; l[2] = t4.z; l[3] = t4.w;
        } else {
            float2 t2 = *(const float2*)(xl + (size_t)src * FO + co);
            l[0] = t2.x; l[1] = t2.y;
        }
        float p = 0.f;
#pragma unroll
        for (int k = 0; k < VEC; ++k) {
            float z = l[k] + r[k];
            z = z > 0.f ? z : NEG_SLOPE * z;
            p += z * a[k];
        }
#pragma unroll
        for (int o = 32; o; o >>= 1) p += __shfl_xor(p, o, 64);
        const float mn = fmaxf(m, p);
        const float sc = __expf(m - mn);
        const float wgt = __expf(p - mn);
        s = s * sc + wgt;
#pragma unroll
        for (int k = 0; k < VEC; ++k) acc[k] = acc[k] * sc + wgt * l[k];
        m = mn;
    }
    const float inv = 1.f / (s + 1e-16f);
#pragma unroll
    for (int k = 0; k < VEC; ++k) {
        float v = acc[k] * inv + bias[co + k];
        if (do_relu) v = fmaxf(v, 0.f);
        acc[k] = v;
    }
    if (outf) {
        if constexpr (VEC == 4)
            *(float4*)(outf + (size_t)d * FO + co) = make_float4(acc[0], acc[1], acc[2], acc[3]);
        else
            *(float2*)(outf + (size_t)d * FO + co) = make_float2(acc[0], acc[1]);
    }
    if (outb) {
        if constexpr (VEC == 4) {
            ushort4 o; o.x = f2b(acc[0]); o.y = f2b(acc[1]); o.z = f2b(acc[2]); o.w = f2b(acc[3]);
            *(ushort4*)(outb + (size_t)d * FO + co) = o;
        } else {
            ushort2 o; o.x = f2b(acc[0]); o.y = f2b(acc[1]);
            *(ushort2*)(outb + (size_t)d * FO + co) = o;
        }
    }
}

// ---- graph boundaries from sorted batch ----
__global__ void gstart_kernel(const int* __restrict__ batch, int* __restrict__ gstart) {
    const int i = blockIdx.x * 256 + threadIdx.x;
    if (i >= N_NODES) return;
    const int b = batch[i];
    if (i == 0) {
        for (int g = 0; g <= b; ++g) gstart[g] = 0;
    } else {
        const int pb = batch[i - 1];
        for (int g = pb + 1; g <= b; ++g) gstart[g] = i;
    }
    if (i == N_NODES - 1) {
        for (int g = b + 1; g <= N_GRAPHS; ++g) gstart[g] = N_NODES;
    }
}

// ---- per-graph pool: one block per graph, zero atomics ----
__global__ __launch_bounds__(128) void pool2_kernel(const float* __restrict__ h,
                                                    const int* __restrict__ gstart,
                                                    float* __restrict__ gsum,
                                                    float* __restrict__ gcnt) {
    const int g = blockIdx.x, t = threadIdx.x;
    const int b = gstart[g], e = gstart[g + 1];
    float s = 0.f;
    for (int i = b; i < e; ++i) s += h[(size_t)i * 128 + t];
    gsum[g * 128 + t] = s;
    if (t == 0) gcnt[g] = (float)(e - b);
}

// ---- fused MLP head ----
__global__ __launch_bounds__(128) void mlp_kernel(
    const float* __restrict__ gsum, const float* __restrict__ gcnt,
    const float* __restrict__ W1, const float* __restrict__ b1,
    const float* __restrict__ W2, const float* __restrict__ b2,
    const float* __restrict__ W3, const float* __restrict__ b3,
    const float* __restrict__ bng_g, const float* __restrict__ bng_b,
    const float* __restrict__ bng_m, const float* __restrict__ bng_v,
    const float* __restrict__ bn1_g, const float* __restrict__ bn1_b,
    const float* __restrict__ bn1_m, const float* __restrict__ bn1_v,
    const float* __restrict__ bn2_g, const float* __restrict__ bn2_b,
    const float* __restrict__ bn2_m, const float* __restrict__ bn2_v,
    float* __restrict__ out) {
    __shared__ float s0[128], s1[128], s2[64];
    const int g = blockIdx.x, t = threadIdx.x;
    const float cnt = fmaxf(gcnt[g], 1.f);
    float v = gsum[g * 128 + t] / cnt;
    v = (v - bng_m[t]) * rsqrtf(bng_v[t] + BN_EPS) * bng_g[t] + bng_b[t];
    s0[t] = v;
    __syncthreads();
    float a1 = b1[t];
    for (int i = 0; i < 128; ++i) a1 += s0[i] * W1[i * 128 + t];
    a1 = fmaxf(a1, 0.f);
    a1 = (a1 - bn1_m[t]) * rsqrtf(bn1_v[t] + BN_EPS) * bn1_g[t] + bn1_b[t];
    s1[t] = a1;
    __syncthreads();
    if (t < 64) {
        float a2 = b2[t];
        for (int i = 0; i < 128; ++i) a2 += s1[i] * W2[i * 64 + t];
        a2 = fmaxf(a2, 0.f);
        a2 = (a2 - bn2_m[t]) * rsqrtf(bn2_v[t] + BN_EPS) * bn2_g[t] + bn2_b[t];
        s2[t] = a2;
    }
    __syncthreads();
    if (t < 2) {
        float a3 = b3[t];
        for (int i = 0; i < 64; ++i) a3 += s2[i] * W3[i * 2 + t];
        out[g * 2 + t] = fmaxf(a3, 0.f);
    }
}

extern "C" void kernel_launch(void* const* d_in, const int* in_sizes, int n_in,
                              void* d_out, int out_size, void* d_ws, size_t ws_size,
                              hipStream_t stream) {
    const float* x = (const float*)d_in[0];
    const int* ei = (const int*)d_in[1];
    const int* batch = (const int*)d_in[2];
    const float* Wl1 = (const float*)d_in[3];
    const float* Wr1 = (const float*)d_in[4];
    const float* att1 = (const float*)d_in[5];
    const float* b1 = (const float*)d_in[6];
    const float* Wl2 = (const float*)d_in[7];
    const float* Wr2 = (const float*)d_in[8];
    const float* att2 = (const float*)d_in[9];
    const float* b2 = (const float*)d_in[10];
    const float* Wl3 = (const float*)d_in[11];
    const float* Wr3 = (const float*)d_in[12];
    const float* att3 = (const float*)d_in[13];
    const float* b3 = (const float*)d_in[14];
    const float* Wlin1 = (const float*)d_in[15];
    const float* blin1 = (const float*)d_in[16];
    const float* Wlin2 = (const float*)d_in[17];
    const float* blin2 = (const float*)d_in[18];
    const float* Wlin3 = (const float*)d_in[19];
    const float* blin3 = (const float*)d_in[20];
    const float* bng_g = (const float*)d_in[21];
    const float* bng_b = (const float*)d_in[22];
    const float* bng_m = (const float*)d_in[23];
    const float* bng_v = (const float*)d_in[24];
    const float* bn1_g = (const float*)d_in[25];
    const float* bn1_b = (const float*)d_in[26];
    const float* bn1_m = (const float*)d_in[27];
    const float* bn1_v = (const float*)d_in[28];
    const float* bn2_g = (const float*)d_in[29];
    const float* bn2_b = (const float*)d_in[30];
    const float* bn2_m = (const float*)d_in[31];
    const float* bn2_v = (const float*)d_in[32];

    float* ws = (float*)d_ws;
    float* slot0 = ws;                                   // xl fp32 (N*256 max)
    float* slot1 = slot0 + (size_t)N_NODES * 256;        // xr fp32 (N*256 max)
    float* h3 = slot1 + (size_t)N_NODES * 128;           // L3 out fp32 (N*128), in slot1's top half
    ushort* hbf = (ushort*)(slot1 + (size_t)N_NODES * 256);  // current-layer input bf16 (N*256)
    ushort* wt = hbf + (size_t)N_NODES * 256;            // 6 transposed bf16 weights
    ushort* wt_l1 = wt;                  // 128*128
    ushort* wt_r1 = wt_l1 + 128 * 128;
    ushort* wt_l2 = wt_r1 + 128 * 128;   // 256*128 (Mt x K)
    ushort* wt_r2 = wt_l2 + 256 * 128;
    ushort* wt_l3 = wt_r2 + 256 * 128;   // 128*256
    ushort* wt_r3 = wt_l3 + 128 * 256;
    int* deg = (int*)(wt_r3 + 128 * 256);                // N
    int* cursor = deg + N_NODES;                         // N
    int* rowp = cursor + N_NODES;                        // N+1
    int* csr_src = rowp + N_NODES + 1;                   // E
    int* gstart = csr_src + N_EDGES;                     // G+1
    float* gsum = (float*)(gstart + N_GRAPHS + 1);       // G*128
    float* gcnt = gsum + (size_t)N_GRAPHS * 128;         // G

    const int eb = (N_EDGES + 255) / 256;

    // ---- CSR build ----
    hipMemsetAsync(deg, 0, N_NODES * 4, stream);
    hipMemsetAsync(cursor, 0, N_NODES * 4, stream);
    deg_count_kernel<<<eb, 256, 0, stream>>>(ei, deg);
    scan_kernel<<<1, 1024, 0, stream>>>(deg, rowp);
    csr_fill_kernel<<<eb, 256, 0, stream>>>(ei, rowp, cursor, csr_src);
    gstart_kernel<<<(N_NODES + 255) / 256, 256, 0, stream>>>(batch, gstart);

    // ---- weight convert+transpose ----
    wcvt_kernel<<<(128 * 128 + 255) / 256, 256, 0, stream>>>(Wl1, wt_l1, 128, 7);
    wcvt_kernel<<<(128 * 128 + 255) / 256, 256, 0, stream>>>(Wr1, wt_r1, 128, 7);
    wcvt_kernel<<<(128 * 256 + 255) / 256, 256, 0, stream>>>(Wl2, wt_l2, 128, 8);
    wcvt_kernel<<<(128 * 256 + 255) / 256, 256, 0, stream>>>(Wr2, wt_r2, 128, 8);
    wcvt_kernel<<<(256 * 128 + 255) / 256, 256, 0, stream>>>(Wl3, wt_l3, 256, 7);
    wcvt_kernel<<<(256 * 128 + 255) / 256, 256, 0, stream>>>(Wr3, wt_r3, 256, 7);

    // ---- x -> bf16 ----
    cvt_kernel<<<(N_NODES * 128 / 4 + 255) / 256, 256, 0, stream>>>(
        x, hbf, N_NODES * 128 / 4);

    const int nb = (N_NODES + 3) / 4;
    const int gx = (N_NODES + 127) / 128;

    // L1: K=128, FO=128
    {
        dim3 gg(gx, 2);
        gemm_bf16_kernel<<<gg, 256, 0, stream>>>(hbf, wt_l1, slot0, N_NODES, 128, 128);
        gemm_bf16_kernel<<<gg, 256, 0, stream>>>(hbf, wt_r1, slot1, N_NODES, 128, 128);
        gat_edge_kernel<128, 2><<<nb, 256, 0, stream>>>(rowp, csr_src, slot0, slot1,
                                                        att1, b1, nullptr, hbf, 1);
    }
    // L2: K=128, FO=256
    {
        dim3 gg(gx, 4);
        gemm_bf16_kernel<<<gg, 256, 0, stream>>>(hbf, wt_l2, slot0, N_NODES, 128, 256);
        gemm_bf16_kernel<<<gg, 256, 0, stream>>>(hbf, wt_r2, slot1, N_NODES, 128, 256);
        gat_edge_kernel<256, 4><<<nb, 256, 0, stream>>>(rowp, csr_src, slot0, slot1,
                                                        att2, b2, nullptr, hbf, 1);
    }
    // L3: K=256, FO=128 -> h3 fp32 (upper half of slot1; xr uses lower half)
    {
        dim3 gg(gx, 2);
        gemm_bf16_kernel<<<gg, 256, 0, stream>>>(hbf, wt_l3, slot0, N_NODES, 256, 128);
        gemm_bf16_kernel<<<gg, 256, 0, stream>>>(hbf, wt_r3, slot1, N_NODES, 256, 128);
        gat_edge_kernel<128, 2><<<nb, 256, 0, stream>>>(rowp, csr_src, slot0, slot1,
                                                        att3, b3, h3, nullptr, 0);
    }

    // pool (no atomics)
    pool2_kernel<<<N_GRAPHS, 128, 0, stream>>>(h3, gstart, gsum, gcnt);

    // MLP head
    mlp_kernel<<<N_GRAPHS, 128, 0, stream>>>(
        gsum, gcnt, Wlin1, blin1, Wlin2, blin2, Wlin3, blin3,
        bng_g, bng_b, bng_m, bng_v, bn1_g, bn1_b, bn1_m, bn1_v,
        bn2_g, bn2_b, bn2_m, bn2_v, (float*)d_out);
}

// Round 4
// 464.389 us; speedup vs baseline: 6.1228x; 1.0651x over previous
//
#include <hip/hip_runtime.h>
#include <math.h>

#define N_NODES 50000
#define N_EDGES 400000
#define N_GRAPHS 512
#define NEG_SLOPE 0.2f
#define BN_EPS 1e-5f

typedef __attribute__((ext_vector_type(8))) short bf16x8;
typedef __attribute__((ext_vector_type(4))) float f32x4;

// ---- fp32 -> bf16 (round-to-nearest-even) ----
__device__ __forceinline__ ushort f2b(float f) {
    unsigned u = __float_as_uint(f);
    unsigned r = (u + 0x7fffu + ((u >> 16) & 1u)) >> 16;
    return (ushort)r;
}
__device__ __forceinline__ float b2f(ushort u) {
    return __uint_as_float((unsigned)u << 16);
}

// ---- activation fp32 -> bf16, vectorized x4 ----
__global__ void cvt_kernel(const float* __restrict__ in, ushort* __restrict__ out,
                           int total4) {
    const int i = blockIdx.x * 256 + threadIdx.x;
    if (i >= total4) return;
    float4 v = *(const float4*)(in + (size_t)i * 4);
    ushort4 o;
    o.x = f2b(v.x); o.y = f2b(v.y); o.z = f2b(v.z); o.w = f2b(v.w);
    *(ushort4*)(out + (size_t)i * 4) = o;
}

// ---- fused weight convert+transpose for all 3 layers ----
// wt_i layout: [2*FO][K] bf16, rows 0..FO-1 = Wl^T, FO..2FO-1 = Wr^T.
__global__ void wcvt_all_kernel(const float* __restrict__ Wl1, const float* __restrict__ Wr1,
                                const float* __restrict__ Wl2, const float* __restrict__ Wr2,
                                const float* __restrict__ Wl3, const float* __restrict__ Wr3,
                                ushort* __restrict__ wt1, ushort* __restrict__ wt2,
                                ushort* __restrict__ wt3) {
    const int i = blockIdx.x * 256 + threadIdx.x;
    if (i < 32768) {                      // L1: 256 rows x 128 k
        const int m = i >> 7, k = i & 127;
        const float v = (m < 128) ? Wl1[k * 128 + m] : Wr1[k * 128 + (m - 128)];
        wt1[i] = f2b(v);
    } else if (i < 98304) {               // L2: 512 rows x 128 k
        const int j = i - 32768;
        const int m = j >> 7, k = j & 127;
        const float v = (m < 256) ? Wl2[k * 256 + m] : Wr2[k * 256 + (m - 256)];
        wt2[j] = f2b(v);
    } else if (i < 163840) {              // L3: 256 rows x 256 k
        const int j = i - 98304;
        const int m = j >> 8, k = j & 255;
        const float v = (m < 128) ? Wl3[k * 128 + m] : Wr3[k * 128 + (m - 128)];
        wt3[j] = f2b(v);
    }
}

// ---- bf16 MFMA GEMM, combined [xl|xr] output ----
// A bf16 [n][K]; Bt bf16 [2*FO][K]; cols<FO -> Cl bf16 [n][FO]; cols>=FO -> Cr fp32 [n][FO].
// Block tile 128x64, 4 waves (wave tile 64x32), BK=32.
__global__ __launch_bounds__(256) void gemm_bf16_kernel(
    const ushort* __restrict__ A, const ushort* __restrict__ Bt,
    ushort* __restrict__ Cl, float* __restrict__ Cr, int n, int K, int FO) {
    __shared__ ushort As[128][40];
    __shared__ ushort Bs[64][40];
    const int tid = threadIdx.x;
    const int row0 = blockIdx.x * 128;
    const int col0 = blockIdx.y * 64;
    const int w = tid >> 6, lane = tid & 63;
    const int wr = (w >> 1) * 64, wc = (w & 1) * 32;
    const int lr = lane & 15, kg = lane >> 4;

    const int arow = tid >> 1, ahalf = tid & 1;
    const int brow = (tid & 127) >> 1, bhalf = tid & 1;

    f32x4 acc[4][2];
#pragma unroll
    for (int i = 0; i < 4; ++i)
#pragma unroll
        for (int j = 0; j < 2; ++j) acc[i][j] = (f32x4){0.f, 0.f, 0.f, 0.f};

    for (int k0 = 0; k0 < K; k0 += 32) {
        {
            const int gr = row0 + arow;
            uint4 v0 = make_uint4(0, 0, 0, 0), v1 = v0;
            if (gr < n) {
                const uint4* p = (const uint4*)(A + (size_t)gr * K + k0) + ahalf * 2;
                v0 = p[0]; v1 = p[1];
            }
            uint4* d = (uint4*)&As[arow][ahalf * 16];
            d[0] = v0; d[1] = v1;
            if (tid < 128) {
                const int gb = col0 + brow;
                const uint4* p = (const uint4*)(Bt + (size_t)gb * K + k0) + bhalf * 2;
                uint4* db = (uint4*)&Bs[brow][bhalf * 16];
                db[0] = p[0]; db[1] = p[1];
            }
        }
        __syncthreads();
        bf16x8 af[4], bfr[2];
#pragma unroll
        for (int mi = 0; mi < 4; ++mi)
            af[mi] = *(const bf16x8*)&As[wr + mi * 16 + lr][kg * 8];
#pragma unroll
        for (int ni = 0; ni < 2; ++ni)
            bfr[ni] = *(const bf16x8*)&Bs[wc + ni * 16 + lr][kg * 8];
#pragma unroll
        for (int mi = 0; mi < 4; ++mi)
#pragma unroll
            for (int ni = 0; ni < 2; ++ni)
                acc[mi][ni] = __builtin_amdgcn_mfma_f32_16x16x32_bf16(
                    af[mi], bfr[ni], acc[mi][ni], 0, 0, 0);
        __syncthreads();
    }
    const bool left = (col0 < FO);
    const int cbase = left ? col0 : col0 - FO;
#pragma unroll
    for (int mi = 0; mi < 4; ++mi)
#pragma unroll
        for (int ni = 0; ni < 2; ++ni)
#pragma unroll
            for (int j = 0; j < 4; ++j) {
                const int r = row0 + wr + mi * 16 + kg * 4 + j;
                if (r < n) {
                    const int c = cbase + wc + ni * 16 + lr;
                    if (left)
                        Cl[(size_t)r * FO + c] = f2b(acc[mi][ni][j]);
                    else
                        Cr[(size_t)r * FO + c] = acc[mi][ni][j];
                }
            }
}

// ---- CSR build ----
__global__ void deg_count_kernel(const int* __restrict__ ei, int* __restrict__ deg) {
    const int e = blockIdx.x * 256 + threadIdx.x;
    if (e < N_EDGES) atomicAdd(&deg[ei[N_EDGES + e]], 1);
}

__global__ __launch_bounds__(1024) void scan_kernel(const int* __restrict__ deg,
                                                    int* __restrict__ rowp) {
    __shared__ int sdata[1024];
    const int t = threadIdx.x;
    const int CH = (N_NODES + 1023) / 1024;
    const int start = t * CH;
    const int end = min(start + CH, N_NODES);
    int sum = 0;
    for (int i = start; i < end; ++i) sum += deg[i];
    sdata[t] = sum;
    __syncthreads();
    for (int off = 1; off < 1024; off <<= 1) {
        int v = (t >= off) ? sdata[t - off] : 0;
        __syncthreads();
        sdata[t] += v;
        __syncthreads();
    }
    int excl = (t == 0) ? 0 : sdata[t - 1];
    for (int i = start; i < end; ++i) { rowp[i] = excl; excl += deg[i]; }
    if (t == 0) rowp[N_NODES] = N_EDGES;
}

__global__ void csr_fill_kernel(const int* __restrict__ ei, const int* __restrict__ rowp,
                                int* __restrict__ cursor, int* __restrict__ csr_src) {
    const int e = blockIdx.x * 256 + threadIdx.x;
    if (e >= N_EDGES) return;
    const int d = ei[N_EDGES + e];
    const int pos = atomicAdd(&cursor[d], 1);
    csr_src[rowp[d] + pos] = ei[e];
}

// ---- fused GATv2 edge phase: per-dst wave, online softmax, bf16 xl gather ----
template <int FO, int VEC>
__global__ __launch_bounds__(256) void gat_edge_kernel(
    const int* __restrict__ rowp, const int* __restrict__ csr_src,
    const ushort* __restrict__ xlb, const float* __restrict__ xr,
    const float* __restrict__ att, const float* __restrict__ bias,
    float* __restrict__ outf, ushort* __restrict__ outb, int do_relu) {
    const int d = blockIdx.x * 4 + (threadIdx.x >> 6);
    const int lane = threadIdx.x & 63;
    if (d >= N_NODES) return;
    const int co = lane * VEC;

    float a[VEC], r[VEC], acc[VEC];
    if constexpr (VEC == 4) {
        float4 t4 = *(const float4*)(att + co);
        a[0] = t4.x; a[1] = t4.y; a[2] = t4.z; a[3] = t4.w;
        t4 = *(const float4*)(xr + (size_t)d * FO + co);
        r[0] = t4.x; r[1] = t4.y; r[2] = t4.z; r[3] = t4.w;
    } else {
        float2 t2 = *(const float2*)(att + co);
        a[0] = t2.x; a[1] = t2.y;
        t2 = *(const float2*)(xr + (size_t)d * FO + co);
        r[0] = t2.x; r[1] = t2.y;
    }
#pragma unroll
    for (int k = 0; k < VEC; ++k) acc[k] = 0.f;

    const int jb = rowp[d], je = rowp[d + 1];
    float m = -INFINITY, s = 0.f;
    for (int j = jb; j < je; ++j) {
        const int src = csr_src[j];
        float l[VEC];
        if constexpr (VEC == 4) {
            ushort4 t4 = *(const ushort4*)(xlb + (size_t)src * FO + co);
            l[0] = b2f(t4.x); l[1] = b2f(t4.y); l[2] = b2f(t4.z); l[3] = b2f(t4.w);
        } else {
            ushort2 t2 = *(const ushort2*)(xlb + (size_t)src * FO + co);
            l[0] = b2f(t2.x); l[1] = b2f(t2.y);
        }
        float p = 0.f;
#pragma unroll
        for (int k = 0; k < VEC; ++k) {
            float z = l[k] + r[k];
            z = z > 0.f ? z : NEG_SLOPE * z;
            p += z * a[k];
        }
#pragma unroll
        for (int o = 32; o; o >>= 1) p += __shfl_xor(p, o, 64);
        if (p > m) {                       // wave-uniform branch
            const float sc = __expf(m - p);  // exp(-inf)=0 handles first edge
            s = s * sc + 1.f;
#pragma unroll
            for (int k = 0; k < VEC; ++k) acc[k] = acc[k] * sc + l[k];
            m = p;
        } else {
            const float wgt = __expf(p - m);
            s += wgt;
#pragma unroll
            for (int k = 0; k < VEC; ++k) acc[k] += wgt * l[k];
        }
    }
    const float inv = 1.f / (s + 1e-16f);
#pragma unroll
    for (int k = 0; k < VEC; ++k) {
        float v = acc[k] * inv + bias[co + k];
        if (do_relu) v = fmaxf(v, 0.f);
        acc[k] = v;
    }
    if (outf) {
        if constexpr (VEC == 4)
            *(float4*)(outf + (size_t)d * FO + co) = make_float4(acc[0], acc[1], acc[2], acc[3]);
        else
            *(float2*)(outf + (size_t)d * FO + co) = make_float2(acc[0], acc[1]);
    }
    if (outb) {
        if constexpr (VEC == 4) {
            ushort4 o; o.x = f2b(acc[0]); o.y = f2b(acc[1]); o.z = f2b(acc[2]); o.w = f2b(acc[3]);
            *(ushort4*)(outb + (size_t)d * FO + co) = o;
        } else {
            ushort2 o; o.x = f2b(acc[0]); o.y = f2b(acc[1]);
            *(ushort2*)(outb + (size_t)d * FO + co) = o;
        }
    }
}

// ---- graph boundaries from sorted batch ----
__global__ void gstart_kernel(const int* __restrict__ batch, int* __restrict__ gstart) {
    const int i = blockIdx.x * 256 + threadIdx.x;
    if (i >= N_NODES) return;
    const int b = batch[i];
    if (i == 0) {
        for (int g = 0; g <= b; ++g) gstart[g] = 0;
    } else {
        const int pb = batch[i - 1];
        for (int g = pb + 1; g <= b; ++g) gstart[g] = i;
    }
    if (i == N_NODES - 1) {
        for (int g = b + 1; g <= N_GRAPHS; ++g) gstart[g] = N_NODES;
    }
}

// ---- per-graph pool: one block per graph, zero atomics ----
__global__ __launch_bounds__(128) void pool2_kernel(const float* __restrict__ h,
                                                    const int* __restrict__ gstart,
                                                    float* __restrict__ gsum,
                                                    float* __restrict__ gcnt) {
    const int g = blockIdx.x, t = threadIdx.x;
    const int b = gstart[g], e = gstart[g + 1];
    float s = 0.f;
    for (int i = b; i < e; ++i) s += h[(size_t)i * 128 + t];
    gsum[g * 128 + t] = s;
    if (t == 0) gcnt[g] = (float)(e - b);
}

// ---- fused MLP head ----
__global__ __launch_bounds__(128) void mlp_kernel(
    const float* __restrict__ gsum, const float* __restrict__ gcnt,
    const float* __restrict__ W1, const float* __restrict__ b1,
    const float* __restrict__ W2, const float* __restrict__ b2,
    const float* __restrict__ W3, const float* __restrict__ b3,
    const float* __restrict__ bng_g, const float* __restrict__ bng_b,
    const float* __restrict__ bng_m, const float* __restrict__ bng_v,
    const float* __restrict__ bn1_g, const float* __restrict__ bn1_b,
    const float* __restrict__ bn1_m, const float* __restrict__ bn1_v,
    const float* __restrict__ bn2_g, const float* __restrict__ bn2_b,
    const float* __restrict__ bn2_m, const float* __restrict__ bn2_v,
    float* __restrict__ out) {
    __shared__ float s0[128], s1[128], s2[64];
    const int g = blockIdx.x, t = threadIdx.x;
    const float cnt = fmaxf(gcnt[g], 1.f);
    float v = gsum[g * 128 + t] / cnt;
    v = (v - bng_m[t]) * rsqrtf(bng_v[t] + BN_EPS) * bng_g[t] + bng_b[t];
    s0[t] = v;
    __syncthreads();
    float a1 = b1[t];
    for (int i = 0; i < 128; ++i) a1 += s0[i] * W1[i * 128 + t];
    a1 = fmaxf(a1, 0.f);
    a1 = (a1 - bn1_m[t]) * rsqrtf(bn1_v[t] + BN_EPS) * bn1_g[t] + bn1_b[t];
    s1[t] = a1;
    __syncthreads();
    if (t < 64) {
        float a2 = b2[t];
        for (int i = 0; i < 128; ++i) a2 += s1[i] * W2[i * 64 + t];
        a2 = fmaxf(a2, 0.f);
        a2 = (a2 - bn2_m[t]) * rsqrtf(bn2_v[t] + BN_EPS) * bn2_g[t] + bn2_b[t];
        s2[t] = a2;
    }
    __syncthreads();
    if (t < 2) {
        float a3 = b3[t];
        for (int i = 0; i < 64; ++i) a3 += s2[i] * W3[i * 2 + t];
        out[g * 2 + t] = fmaxf(a3, 0.f);
    }
}

extern "C" void kernel_launch(void* const* d_in, const int* in_sizes, int n_in,
                              void* d_out, int out_size, void* d_ws, size_t ws_size,
                              hipStream_t stream) {
    const float* x = (const float*)d_in[0];
    const int* ei = (const int*)d_in[1];
    const int* batch = (const int*)d_in[2];
    const float* Wl1 = (const float*)d_in[3];
    const float* Wr1 = (const float*)d_in[4];
    const float* att1 = (const float*)d_in[5];
    const float* b1 = (const float*)d_in[6];
    const float* Wl2 = (const float*)d_in[7];
    const float* Wr2 = (const float*)d_in[8];
    const float* att2 = (const float*)d_in[9];
    const float* b2 = (const float*)d_in[10];
    const float* Wl3 = (const float*)d_in[11];
    const float* Wr3 = (const float*)d_in[12];
    const float* att3 = (const float*)d_in[13];
    const float* b3 = (const float*)d_in[14];
    const float* Wlin1 = (const float*)d_in[15];
    const float* blin1 = (const float*)d_in[16];
    const float* Wlin2 = (const float*)d_in[17];
    const float* blin2 = (const float*)d_in[18];
    const float* Wlin3 = (const float*)d_in[19];
    const float* blin3 = (const float*)d_in[20];
    const float* bng_g = (const float*)d_in[21];
    const float* bng_b = (const float*)d_in[22];
    const float* bng_m = (const float*)d_in[23];
    const float* bng_v = (const float*)d_in[24];
    const float* bn1_g = (const float*)d_in[25];
    const float* bn1_b = (const float*)d_in[26];
    const float* bn1_m = (const float*)d_in[27];
    const float* bn1_v = (const float*)d_in[28];
    const float* bn2_g = (const float*)d_in[29];
    const float* bn2_b = (const float*)d_in[30];
    const float* bn2_m = (const float*)d_in[31];
    const float* bn2_v = (const float*)d_in[32];

    float* ws = (float*)d_ws;
    ushort* xlb = (ushort*)ws;                           // bf16 xl (N*256 max)
    float* xr = (float*)(xlb + (size_t)N_NODES * 256);   // fp32 xr (N*256 max)
    float* h3 = xr + (size_t)N_NODES * 256;              // fp32 L3 out (N*128)
    ushort* hbf = (ushort*)(h3 + (size_t)N_NODES * 128); // bf16 layer input (N*256)
    ushort* wt1 = hbf + (size_t)N_NODES * 256;           // 256*128
    ushort* wt2 = wt1 + 256 * 128;                       // 512*128
    ushort* wt3 = wt2 + 512 * 128;                       // 256*256
    int* deg = (int*)(wt3 + 256 * 256);                  // N
    int* cursor = deg + N_NODES;                         // N
    int* rowp = cursor + N_NODES;                        // N+1
    int* csr_src = rowp + N_NODES + 1;                   // E
    int* gstart = csr_src + N_EDGES;                     // G+1
    float* gsum = (float*)(gstart + N_GRAPHS + 1);       // G*128
    float* gcnt = gsum + (size_t)N_GRAPHS * 128;         // G

    const int eb = (N_EDGES + 255) / 256;

    // ---- CSR build ----
    hipMemsetAsync(deg, 0, (size_t)N_NODES * 2 * 4, stream);  // deg + cursor
    deg_count_kernel<<<eb, 256, 0, stream>>>(ei, deg);
    scan_kernel<<<1, 1024, 0, stream>>>(deg, rowp);
    csr_fill_kernel<<<eb, 256, 0, stream>>>(ei, rowp, cursor, csr_src);
    gstart_kernel<<<(N_NODES + 255) / 256, 256, 0, stream>>>(batch, gstart);

    // ---- weights + x -> bf16 ----
    wcvt_all_kernel<<<640, 256, 0, stream>>>(Wl1, Wr1, Wl2, Wr2, Wl3, Wr3, wt1, wt2, wt3);
    cvt_kernel<<<(N_NODES * 128 / 4 + 255) / 256, 256, 0, stream>>>(
        x, hbf, N_NODES * 128 / 4);

    const int nb = (N_NODES + 3) / 4;
    const int gx = (N_NODES + 127) / 128;

    // L1: K=128, FO=128
    gemm_bf16_kernel<<<dim3(gx, 4), 256, 0, stream>>>(hbf, wt1, xlb, xr, N_NODES, 128, 128);
    gat_edge_kernel<128, 2><<<nb, 256, 0, stream>>>(rowp, csr_src, xlb, xr,
                                                    att1, b1, nullptr, hbf, 1);
    // L2: K=128, FO=256
    gemm_bf16_kernel<<<dim3(gx, 8), 256, 0, stream>>>(hbf, wt2, xlb, xr, N_NODES, 128, 256);
    gat_edge_kernel<256, 4><<<nb, 256, 0, stream>>>(rowp, csr_src, xlb, xr,
                                                    att2, b2, nullptr, hbf, 1);
    // L3: K=256, FO=128 -> h3 fp32
    gemm_bf16_kernel<<<dim3(gx, 4), 256, 0, stream>>>(hbf, wt3, xlb, xr, N_NODES, 256, 128);
    gat_edge_kernel<128, 2><<<nb, 256, 0, stream>>>(rowp, csr_src, xlb, xr,
                                                    att3, b3, h3, nullptr, 0);

    // pool (no atomics)
    pool2_kernel<<<N_GRAPHS, 128, 0, stream>>>(h3, gstart, gsum, gcnt);

    // MLP head
    mlp_kernel<<<N_GRAPHS, 128, 0, stream>>>(
        gsum, gcnt, Wlin1, blin1, Wlin2, blin2, Wlin3, blin3,
        bng_g, bng_b, bng_m, bng_v, bn1_g, bn1_b, bn1_m, bn1_v,
        bn2_g, bn2_b, bn2_m, bn2_v, (float*)d_out);
}

// Round 5
// 373.328 us; speedup vs baseline: 7.6163x; 1.2439x over previous
//
#include <hip/hip_runtime.h>
#include <math.h>

#define N_NODES 50000
#define N_EDGES 400000
#define N_GRAPHS 512
#define NEG_SLOPE 0.2f
#define BN_EPS 1e-5f
#define SCAN_BLOCKS 49   // ceil(50000/1024)

typedef __attribute__((ext_vector_type(8))) short bf16x8;
typedef __attribute__((ext_vector_type(4))) float f32x4;

// ---- fp32 -> bf16 (round-to-nearest-even) ----
__device__ __forceinline__ ushort f2b(float f) {
    unsigned u = __float_as_uint(f);
    unsigned r = (u + 0x7fffu + ((u >> 16) & 1u)) >> 16;
    return (ushort)r;
}
__device__ __forceinline__ float b2f(ushort u) {
    return __uint_as_float((unsigned)u << 16);
}

// ---- activation fp32 -> bf16, vectorized x4 ----
__global__ void cvt_kernel(const float* __restrict__ in, ushort* __restrict__ out,
                           int total4) {
    const int i = blockIdx.x * 256 + threadIdx.x;
    if (i >= total4) return;
    float4 v = *(const float4*)(in + (size_t)i * 4);
    ushort4 o;
    o.x = f2b(v.x); o.y = f2b(v.y); o.z = f2b(v.z); o.w = f2b(v.w);
    *(ushort4*)(out + (size_t)i * 4) = o;
}

// ---- fused weight convert+transpose for all 3 layers ----
// wt_i layout: [2*FO][K] bf16, rows 0..FO-1 = Wl^T, FO..2FO-1 = Wr^T.
__global__ void wcvt_all_kernel(const float* __restrict__ Wl1, const float* __restrict__ Wr1,
                                const float* __restrict__ Wl2, const float* __restrict__ Wr2,
                                const float* __restrict__ Wl3, const float* __restrict__ Wr3,
                                ushort* __restrict__ wt1, ushort* __restrict__ wt2,
                                ushort* __restrict__ wt3) {
    const int i = blockIdx.x * 256 + threadIdx.x;
    if (i < 32768) {                      // L1: 256 rows x 128 k
        const int m = i >> 7, k = i & 127;
        const float v = (m < 128) ? Wl1[k * 128 + m] : Wr1[k * 128 + (m - 128)];
        wt1[i] = f2b(v);
    } else if (i < 98304) {               // L2: 512 rows x 128 k
        const int j = i - 32768;
        const int m = j >> 7, k = j & 127;
        const float v = (m < 256) ? Wl2[k * 256 + m] : Wr2[k * 256 + (m - 256)];
        wt2[j] = f2b(v);
    } else if (i < 163840) {              // L3: 256 rows x 256 k
        const int j = i - 98304;
        const int m = j >> 8, k = j & 255;
        const float v = (m < 128) ? Wl3[k * 128 + m] : Wr3[k * 128 + (m - 128)];
        wt3[j] = f2b(v);
    }
}

// ---- bf16 MFMA GEMM, combined [xl|xr] output ----
// A bf16 [n][K]; Bt bf16 [2*FO][K]; cols<FO -> Cl bf16 [n][FO]; cols>=FO -> Cr fp32.
// Block tile 128x128, 4 waves (wave tile 64x64), BK=32.
__global__ __launch_bounds__(256) void gemm_bf16_kernel(
    const ushort* __restrict__ A, const ushort* __restrict__ Bt,
    ushort* __restrict__ Cl, float* __restrict__ Cr, int n, int K, int FO) {
    __shared__ ushort As[128][40];
    __shared__ ushort Bs[128][40];
    const int tid = threadIdx.x;
    const int row0 = blockIdx.x * 128;
    const int col0 = blockIdx.y * 128;
    const int w = tid >> 6, lane = tid & 63;
    const int wr = (w >> 1) * 64, wc = (w & 1) * 64;
    const int lr = lane & 15, kg = lane >> 4;

    const int srow = tid >> 1, shalf = tid & 1;  // 128 rows x 2 x 32B, for both A and B

    f32x4 acc[4][4];
#pragma unroll
    for (int i = 0; i < 4; ++i)
#pragma unroll
        for (int j = 0; j < 4; ++j) acc[i][j] = (f32x4){0.f, 0.f, 0.f, 0.f};

    for (int k0 = 0; k0 < K; k0 += 32) {
        {
            const int gr = row0 + srow;
            uint4 v0 = make_uint4(0, 0, 0, 0), v1 = v0;
            if (gr < n) {
                const uint4* p = (const uint4*)(A + (size_t)gr * K + k0) + shalf * 2;
                v0 = p[0]; v1 = p[1];
            }
            uint4* d = (uint4*)&As[srow][shalf * 16];
            d[0] = v0; d[1] = v1;
            const int gb = col0 + srow;   // B rows always in bounds (2*FO % 128 == 0)
            const uint4* p = (const uint4*)(Bt + (size_t)gb * K + k0) + shalf * 2;
            uint4* db = (uint4*)&Bs[srow][shalf * 16];
            db[0] = p[0]; db[1] = p[1];
        }
        __syncthreads();
        bf16x8 af[4], bfr[4];
#pragma unroll
        for (int mi = 0; mi < 4; ++mi)
            af[mi] = *(const bf16x8*)&As[wr + mi * 16 + lr][kg * 8];
#pragma unroll
        for (int ni = 0; ni < 4; ++ni)
            bfr[ni] = *(const bf16x8*)&Bs[wc + ni * 16 + lr][kg * 8];
#pragma unroll
        for (int mi = 0; mi < 4; ++mi)
#pragma unroll
            for (int ni = 0; ni < 4; ++ni)
                acc[mi][ni] = __builtin_amdgcn_mfma_f32_16x16x32_bf16(
                    af[mi], bfr[ni], acc[mi][ni], 0, 0, 0);
        __syncthreads();
    }
    const bool left = (col0 < FO);
    const int cbase = left ? col0 : col0 - FO;
#pragma unroll
    for (int mi = 0; mi < 4; ++mi)
#pragma unroll
        for (int ni = 0; ni < 4; ++ni)
#pragma unroll
            for (int j = 0; j < 4; ++j) {
                const int r = row0 + wr + mi * 16 + kg * 4 + j;
                if (r < n) {
                    const int c = cbase + wc + ni * 16 + lr;
                    if (left)
                        Cl[(size_t)r * FO + c] = f2b(acc[mi][ni][j]);
                    else
                        Cr[(size_t)r * FO + c] = acc[mi][ni][j];
                }
            }
}

// ---- CSR build ----
__global__ void deg_count_kernel(const int* __restrict__ ei, int* __restrict__ deg) {
    const int e = blockIdx.x * 256 + threadIdx.x;
    if (e < N_EDGES) atomicAdd(&deg[ei[N_EDGES + e]], 1);
}

// hierarchical exclusive scan, stage A: per-block (1024 elems) scan + block sums
__global__ __launch_bounds__(256) void scanA_kernel(const int* __restrict__ deg,
                                                    int* __restrict__ rowp,
                                                    int* __restrict__ bsum) {
    const int t = threadIdx.x, b = blockIdx.x;
    const int i0 = b * 1024 + t * 4;
    int4 d = make_int4(0, 0, 0, 0);
    if (i0 + 3 < N_NODES) d = *(const int4*)(deg + i0);
    else {
        if (i0 + 0 < N_NODES) d.x = deg[i0 + 0];
        if (i0 + 1 < N_NODES) d.y = deg[i0 + 1];
        if (i0 + 2 < N_NODES) d.z = deg[i0 + 2];
    }
    const int tsum = d.x + d.y + d.z + d.w;
    int inc = tsum;
    const int lane = t & 63, wave = t >> 6;
#pragma unroll
    for (int o = 1; o < 64; o <<= 1) {
        int v = __shfl_up(inc, o, 64);
        if (lane >= o) inc += v;
    }
    __shared__ int wsum[4];
    if (lane == 63) wsum[wave] = inc;
    __syncthreads();
    int wbase = 0;
#pragma unroll
    for (int ww = 0; ww < 4; ++ww)
        if (ww < wave) wbase += wsum[ww];
    const int texcl = wbase + inc - tsum;
    int4 o4;
    o4.x = texcl;
    o4.y = o4.x + d.x;
    o4.z = o4.y + d.y;
    o4.w = o4.z + d.z;
    if (i0 + 3 < N_NODES) *(int4*)(rowp + i0) = o4;
    else {
        if (i0 + 0 < N_NODES) rowp[i0 + 0] = o4.x;
        if (i0 + 1 < N_NODES) rowp[i0 + 1] = o4.y;
        if (i0 + 2 < N_NODES) rowp[i0 + 2] = o4.z;
    }
    if (t == 255) bsum[b] = wbase + inc;
}

// stage C: add exclusive block base (reduced in-block; SCAN_BLOCKS<=64)
__global__ __launch_bounds__(256) void scanC_kernel(const int* __restrict__ bsum,
                                                    int* __restrict__ rowp) {
    const int t = threadIdx.x, b = blockIdx.x;
    __shared__ int base_s;
    if (t < 64) {
        int v = (t < b) ? bsum[t] : 0;
#pragma unroll
        for (int o = 32; o; o >>= 1) v += __shfl_xor(v, o, 64);
        if (t == 0) base_s = v;
    }
    __syncthreads();
    const int base = base_s;
    const int i0 = b * 1024 + t * 4;
    if (base != 0) {
        if (i0 + 3 < N_NODES) {
            int4 v = *(int4*)(rowp + i0);
            v.x += base; v.y += base; v.z += base; v.w += base;
            *(int4*)(rowp + i0) = v;
        } else {
            if (i0 + 0 < N_NODES) rowp[i0 + 0] += base;
            if (i0 + 1 < N_NODES) rowp[i0 + 1] += base;
            if (i0 + 2 < N_NODES) rowp[i0 + 2] += base;
        }
    }
    if (b == 0 && t == 0) rowp[N_NODES] = N_EDGES;
}

__global__ void csr_fill_kernel(const int* __restrict__ ei, const int* __restrict__ rowp,
                                int* __restrict__ cursor, int* __restrict__ csr_src) {
    const int e = blockIdx.x * 256 + threadIdx.x;
    if (e >= N_EDGES) return;
    const int d = ei[N_EDGES + e];
    const int pos = atomicAdd(&cursor[d], 1);
    csr_src[rowp[d] + pos] = ei[e];
}

// ---- fused GATv2 edge phase: per-dst wave, online softmax, bf16 xl gather ----
template <int FO, int VEC>
__global__ __launch_bounds__(256) void gat_edge_kernel(
    const int* __restrict__ rowp, const int* __restrict__ csr_src,
    const ushort* __restrict__ xlb, const float* __restrict__ xr,
    const float* __restrict__ att, const float* __restrict__ bias,
    float* __restrict__ outf, ushort* __restrict__ outb, int do_relu) {
    const int d = blockIdx.x * 4 + (threadIdx.x >> 6);
    const int lane = threadIdx.x & 63;
    if (d >= N_NODES) return;
    const int co = lane * VEC;

    float a[VEC], r[VEC], acc[VEC];
    if constexpr (VEC == 4) {
        float4 t4 = *(const float4*)(att + co);
        a[0] = t4.x; a[1] = t4.y; a[2] = t4.z; a[3] = t4.w;
        t4 = *(const float4*)(xr + (size_t)d * FO + co);
        r[0] = t4.x; r[1] = t4.y; r[2] = t4.z; r[3] = t4.w;
    } else {
        float2 t2 = *(const float2*)(att + co);
        a[0] = t2.x; a[1] = t2.y;
        t2 = *(const float2*)(xr + (size_t)d * FO + co);
        r[0] = t2.x; r[1] = t2.y;
    }
#pragma unroll
    for (int k = 0; k < VEC; ++k) acc[k] = 0.f;

    const int jb = rowp[d], je = rowp[d + 1];
    float m = -INFINITY, s = 0.f;
    for (int j = jb; j < je; ++j) {
        const int src = csr_src[j];
        float l[VEC];
        if constexpr (VEC == 4) {
            ushort4 t4 = *(const ushort4*)(xlb + (size_t)src * FO + co);
            l[0] = b2f(t4.x); l[1] = b2f(t4.y); l[2] = b2f(t4.z); l[3] = b2f(t4.w);
        } else {
            ushort2 t2 = *(const ushort2*)(xlb + (size_t)src * FO + co);
            l[0] = b2f(t2.x); l[1] = b2f(t2.y);
        }
        float p = 0.f;
#pragma unroll
        for (int k = 0; k < VEC; ++k) {
            float z = l[k] + r[k];
            z = z > 0.f ? z : NEG_SLOPE * z;
            p += z * a[k];
        }
#pragma unroll
        for (int o = 32; o; o >>= 1) p += __shfl_xor(p, o, 64);
        if (p > m) {                       // wave-uniform branch
            const float sc = __expf(m - p);  // exp(-inf)=0 handles first edge
            s = s * sc + 1.f;
#pragma unroll
            for (int k = 0; k < VEC; ++k) acc[k] = acc[k] * sc + l[k];
            m = p;
        } else {
            const float wgt = __expf(p - m);
            s += wgt;
#pragma unroll
            for (int k = 0; k < VEC; ++k) acc[k] += wgt * l[k];
        }
    }
    const float inv = 1.f / (s + 1e-16f);
#pragma unroll
    for (int k = 0; k < VEC; ++k) {
        float v = acc[k] * inv + bias[co + k];
        if (do_relu) v = fmaxf(v, 0.f);
        acc[k] = v;
    }
    if (outf) {
        if constexpr (VEC == 4)
            *(float4*)(outf + (size_t)d * FO + co) = make_float4(acc[0], acc[1], acc[2], acc[3]);
        else
            *(float2*)(outf + (size_t)d * FO + co) = make_float2(acc[0], acc[1]);
    }
    if (outb) {
        if constexpr (VEC == 4) {
            ushort4 o; o.x = f2b(acc[0]); o.y = f2b(acc[1]); o.z = f2b(acc[2]); o.w = f2b(acc[3]);
            *(ushort4*)(outb + (size_t)d * FO + co) = o;
        } else {
            ushort2 o; o.x = f2b(acc[0]); o.y = f2b(acc[1]);
            *(ushort2*)(outb + (size_t)d * FO + co) = o;
        }
    }
}

// ---- graph boundaries from sorted batch ----
__global__ void gstart_kernel(const int* __restrict__ batch, int* __restrict__ gstart) {
    const int i = blockIdx.x * 256 + threadIdx.x;
    if (i >= N_NODES) return;
    const int b = batch[i];
    if (i == 0) {
        for (int g = 0; g <= b; ++g) gstart[g] = 0;
    } else {
        const int pb = batch[i - 1];
        for (int g = pb + 1; g <= b; ++g) gstart[g] = i;
    }
    if (i == N_NODES - 1) {
        for (int g = b + 1; g <= N_GRAPHS; ++g) gstart[g] = N_NODES;
    }
}

// ---- per-graph pool: one block per graph, zero atomics ----
__global__ __launch_bounds__(128) void pool2_kernel(const float* __restrict__ h,
                                                    const int* __restrict__ gstart,
                                                    float* __restrict__ gsum,
                                                    float* __restrict__ gcnt) {
    const int g = blockIdx.x, t = threadIdx.x;
    const int b = gstart[g], e = gstart[g + 1];
    float s = 0.f;
    for (int i = b; i < e; ++i) s += h[(size_t)i * 128 + t];
    gsum[g * 128 + t] = s;
    if (t == 0) gcnt[g] = (float)(e - b);
}

// ---- fused MLP head ----
__global__ __launch_bounds__(128) void mlp_kernel(
    const float* __restrict__ gsum, const float* __restrict__ gcnt,
    const float* __restrict__ W1, const float* __restrict__ b1,
    const float* __restrict__ W2, const float* __restrict__ b2,
    const float* __restrict__ W3, const float* __restrict__ b3,
    const float* __restrict__ bng_g, const float* __restrict__ bng_b,
    const float* __restrict__ bng_m, const float* __restrict__ bng_v,
    const float* __restrict__ bn1_g, const float* __restrict__ bn1_b,
    const float* __restrict__ bn1_m, const float* __restrict__ bn1_v,
    const float* __restrict__ bn2_g, const float* __restrict__ bn2_b,
    const float* __restrict__ bn2_m, const float* __restrict__ bn2_v,
    float* __restrict__ out) {
    __shared__ float s0[128], s1[128], s2[64];
    const int g = blockIdx.x, t = threadIdx.x;
    const float cnt = fmaxf(gcnt[g], 1.f);
    float v = gsum[g * 128 + t] / cnt;
    v = (v - bng_m[t]) * rsqrtf(bng_v[t] + BN_EPS) * bng_g[t] + bng_b[t];
    s0[t] = v;
    __syncthreads();
    float a1 = b1[t];
    for (int i = 0; i < 128; ++i) a1 += s0[i] * W1[i * 128 + t];
    a1 = fmaxf(a1, 0.f);
    a1 = (a1 - bn1_m[t]) * rsqrtf(bn1_v[t] + BN_EPS) * bn1_g[t] + bn1_b[t];
    s1[t] = a1;
    __syncthreads();
    if (t < 64) {
        float a2 = b2[t];
        for (int i = 0; i < 128; ++i) a2 += s1[i] * W2[i * 64 + t];
        a2 = fmaxf(a2, 0.f);
        a2 = (a2 - bn2_m[t]) * rsqrtf(bn2_v[t] + BN_EPS) * bn2_g[t] + bn2_b[t];
        s2[t] = a2;
    }
    __syncthreads();
    if (t < 2) {
        float a3 = b3[t];
        for (int i = 0; i < 64; ++i) a3 += s2[i] * W3[i * 2 + t];
        out[g * 2 + t] = fmaxf(a3, 0.f);
    }
}

extern "C" void kernel_launch(void* const* d_in, const int* in_sizes, int n_in,
                              void* d_out, int out_size, void* d_ws, size_t ws_size,
                              hipStream_t stream) {
    const float* x = (const float*)d_in[0];
    const int* ei = (const int*)d_in[1];
    const int* batch = (const int*)d_in[2];
    const float* Wl1 = (const float*)d_in[3];
    const float* Wr1 = (const float*)d_in[4];
    const float* att1 = (const float*)d_in[5];
    const float* b1 = (const float*)d_in[6];
    const float* Wl2 = (const float*)d_in[7];
    const float* Wr2 = (const float*)d_in[8];
    const float* att2 = (const float*)d_in[9];
    const float* b2 = (const float*)d_in[10];
    const float* Wl3 = (const float*)d_in[11];
    const float* Wr3 = (const float*)d_in[12];
    const float* att3 = (const float*)d_in[13];
    const float* b3 = (const float*)d_in[14];
    const float* Wlin1 = (const float*)d_in[15];
    const float* blin1 = (const float*)d_in[16];
    const float* Wlin2 = (const float*)d_in[17];
    const float* blin2 = (const float*)d_in[18];
    const float* Wlin3 = (const float*)d_in[19];
    const float* blin3 = (const float*)d_in[20];
    const float* bng_g = (const float*)d_in[21];
    const float* bng_b = (const float*)d_in[22];
    const float* bng_m = (const float*)d_in[23];
    const float* bng_v = (const float*)d_in[24];
    const float* bn1_g = (const float*)d_in[25];
    const float* bn1_b = (const float*)d_in[26];
    const float* bn1_m = (const float*)d_in[27];
    const float* bn1_v = (const float*)d_in[28];
    const float* bn2_g = (const float*)d_in[29];
    const float* bn2_b = (const float*)d_in[30];
    const float* bn2_m = (const float*)d_in[31];
    const float* bn2_v = (const float*)d_in[32];

    float* ws = (float*)d_ws;
    ushort* xlb = (ushort*)ws;                           // bf16 xl (N*256 max)
    float* xr = (float*)(xlb + (size_t)N_NODES * 256);   // fp32 xr (N*256 max)
    float* h3 = xr + (size_t)N_NODES * 256;              // fp32 L3 out (N*128)
    ushort* hbf = (ushort*)(h3 + (size_t)N_NODES * 128); // bf16 layer input (N*256)
    ushort* wt1 = hbf + (size_t)N_NODES * 256;           // 256*128
    ushort* wt2 = wt1 + 256 * 128;                       // 512*128
    ushort* wt3 = wt2 + 512 * 128;                       // 256*256
    int* deg = (int*)(wt3 + 256 * 256);                  // N
    int* cursor = deg + N_NODES;                         // N
    int* rowp = cursor + N_NODES;                        // N+1
    int* csr_src = rowp + N_NODES + 1;                   // E
    int* gstart = csr_src + N_EDGES;                     // G+1
    int* bsum = gstart + N_GRAPHS + 1;                   // SCAN_BLOCKS
    float* gsum = (float*)(bsum + SCAN_BLOCKS);          // G*128
    float* gcnt = gsum + (size_t)N_GRAPHS * 128;         // G

    const int eb = (N_EDGES + 255) / 256;

    // ---- CSR build (hierarchical scan) ----
    hipMemsetAsync(deg, 0, (size_t)N_NODES * 2 * 4, stream);  // deg + cursor
    deg_count_kernel<<<eb, 256, 0, stream>>>(ei, deg);
    scanA_kernel<<<SCAN_BLOCKS, 256, 0, stream>>>(deg, rowp, bsum);
    scanC_kernel<<<SCAN_BLOCKS, 256, 0, stream>>>(bsum, rowp);
    csr_fill_kernel<<<eb, 256, 0, stream>>>(ei, rowp, cursor, csr_src);
    gstart_kernel<<<(N_NODES + 255) / 256, 256, 0, stream>>>(batch, gstart);

    // ---- weights + x -> bf16 ----
    wcvt_all_kernel<<<640, 256, 0, stream>>>(Wl1, Wr1, Wl2, Wr2, Wl3, Wr3, wt1, wt2, wt3);
    cvt_kernel<<<(N_NODES * 128 / 4 + 255) / 256, 256, 0, stream>>>(
        x, hbf, N_NODES * 128 / 4);

    const int nb = (N_NODES + 3) / 4;
    const int gx = (N_NODES + 127) / 128;

    // L1: K=128, FO=128
    gemm_bf16_kernel<<<dim3(gx, 2), 256, 0, stream>>>(hbf, wt1, xlb, xr, N_NODES, 128, 128);
    gat_edge_kernel<128, 2><<<nb, 256, 0, stream>>>(rowp, csr_src, xlb, xr,
                                                    att1, b1, nullptr, hbf, 1);
    // L2: K=128, FO=256
    gemm_bf16_kernel<<<dim3(gx, 4), 256, 0, stream>>>(hbf, wt2, xlb, xr, N_NODES, 128, 256);
    gat_edge_kernel<256, 4><<<nb, 256, 0, stream>>>(rowp, csr_src, xlb, xr,
                                                    att2, b2, nullptr, hbf, 1);
    // L3: K=256, FO=128 -> h3 fp32
    gemm_bf16_kernel<<<dim3(gx, 2), 256, 0, stream>>>(hbf, wt3, xlb, xr, N_NODES, 256, 128);
    gat_edge_kernel<128, 2><<<nb, 256, 0, stream>>>(rowp, csr_src, xlb, xr,
                                                    att3, b3, h3, nullptr, 0);

    // pool (no atomics)
    pool2_kernel<<<N_GRAPHS, 128, 0, stream>>>(h3, gstart, gsum, gcnt);

    // MLP head
    mlp_kernel<<<N_GRAPHS, 128, 0, stream>>>(
        gsum, gcnt, Wlin1, blin1, Wlin2, blin2, Wlin3, blin3,
        bng_g, bng_b, bng_m, bng_v, bn1_g, bn1_b, bn1_m, bn1_v,
        bn2_g, bn2_b, bn2_m, bn2_v, (float*)d_out);
}

// Round 6
// 321.133 us; speedup vs baseline: 8.8542x; 1.1625x over previous
//
#include <hip/hip_runtime.h>
#include <math.h>

#define N_NODES 50000
#define N_EDGES 400000
#define N_GRAPHS 512
#define NEG_SLOPE 0.2f
#define BN_EPS 1e-5f
#define SCAN_BLOCKS 49   // ceil(50000/1024)

typedef __attribute__((ext_vector_type(8))) short bf16x8;
typedef __attribute__((ext_vector_type(4))) float f32x4;

// ---- fp32 -> bf16 (round-to-nearest-even) ----
__device__ __forceinline__ ushort f2b(float f) {
    unsigned u = __float_as_uint(f);
    unsigned r = (u + 0x7fffu + ((u >> 16) & 1u)) >> 16;
    return (ushort)r;
}
__device__ __forceinline__ float b2f(ushort u) {
    return __uint_as_float((unsigned)u << 16);
}

// ---- activation fp32 -> bf16, vectorized x4 ----
__global__ void cvt_kernel(const float* __restrict__ in, ushort* __restrict__ out,
                           int total4) {
    const int i = blockIdx.x * 256 + threadIdx.x;
    if (i >= total4) return;
    float4 v = *(const float4*)(in + (size_t)i * 4);
    ushort4 o;
    o.x = f2b(v.x); o.y = f2b(v.y); o.z = f2b(v.z); o.w = f2b(v.w);
    *(ushort4*)(out + (size_t)i * 4) = o;
}

// ---- fused weight convert+transpose for all 3 layers ----
__global__ void wcvt_all_kernel(const float* __restrict__ Wl1, const float* __restrict__ Wr1,
                                const float* __restrict__ Wl2, const float* __restrict__ Wr2,
                                const float* __restrict__ Wl3, const float* __restrict__ Wr3,
                                ushort* __restrict__ wt1, ushort* __restrict__ wt2,
                                ushort* __restrict__ wt3) {
    const int i = blockIdx.x * 256 + threadIdx.x;
    if (i < 32768) {
        const int m = i >> 7, k = i & 127;
        const float v = (m < 128) ? Wl1[k * 128 + m] : Wr1[k * 128 + (m - 128)];
        wt1[i] = f2b(v);
    } else if (i < 98304) {
        const int j = i - 32768;
        const int m = j >> 7, k = j & 127;
        const float v = (m < 256) ? Wl2[k * 256 + m] : Wr2[k * 256 + (m - 256)];
        wt2[j] = f2b(v);
    } else if (i < 163840) {
        const int j = i - 98304;
        const int m = j >> 8, k = j & 255;
        const float v = (m < 128) ? Wl3[k * 128 + m] : Wr3[k * 128 + (m - 128)];
        wt3[j] = f2b(v);
    }
}

// ---- bf16 MFMA GEMM, combined [xl|xr] output ----
__global__ __launch_bounds__(256) void gemm_bf16_kernel(
    const ushort* __restrict__ A, const ushort* __restrict__ Bt,
    ushort* __restrict__ Cl, float* __restrict__ Cr, int n, int K, int FO) {
    __shared__ ushort As[128][40];
    __shared__ ushort Bs[128][40];
    const int tid = threadIdx.x;
    const int row0 = blockIdx.x * 128;
    const int col0 = blockIdx.y * 128;
    const int w = tid >> 6, lane = tid & 63;
    const int wr = (w >> 1) * 64, wc = (w & 1) * 64;
    const int lr = lane & 15, kg = lane >> 4;

    const int srow = tid >> 1, shalf = tid & 1;

    f32x4 acc[4][4];
#pragma unroll
    for (int i = 0; i < 4; ++i)
#pragma unroll
        for (int j = 0; j < 4; ++j) acc[i][j] = (f32x4){0.f, 0.f, 0.f, 0.f};

    for (int k0 = 0; k0 < K; k0 += 32) {
        {
            const int gr = row0 + srow;
            uint4 v0 = make_uint4(0, 0, 0, 0), v1 = v0;
            if (gr < n) {
                const uint4* p = (const uint4*)(A + (size_t)gr * K + k0) + shalf * 2;
                v0 = p[0]; v1 = p[1];
            }
            uint4* d = (uint4*)&As[srow][shalf * 16];
            d[0] = v0; d[1] = v1;
            const int gb = col0 + srow;
            const uint4* p = (const uint4*)(Bt + (size_t)gb * K + k0) + shalf * 2;
            uint4* db = (uint4*)&Bs[srow][shalf * 16];
            db[0] = p[0]; db[1] = p[1];
        }
        __syncthreads();
        bf16x8 af[4], bfr[4];
#pragma unroll
        for (int mi = 0; mi < 4; ++mi)
            af[mi] = *(const bf16x8*)&As[wr + mi * 16 + lr][kg * 8];
#pragma unroll
        for (int ni = 0; ni < 4; ++ni)
            bfr[ni] = *(const bf16x8*)&Bs[wc + ni * 16 + lr][kg * 8];
#pragma unroll
        for (int mi = 0; mi < 4; ++mi)
#pragma unroll
            for (int ni = 0; ni < 4; ++ni)
                acc[mi][ni] = __builtin_amdgcn_mfma_f32_16x16x32_bf16(
                    af[mi], bfr[ni], acc[mi][ni], 0, 0, 0);
        __syncthreads();
    }
    const bool left = (col0 < FO);
    const int cbase = left ? col0 : col0 - FO;
#pragma unroll
    for (int mi = 0; mi < 4; ++mi)
#pragma unroll
        for (int ni = 0; ni < 4; ++ni)
#pragma unroll
            for (int j = 0; j < 4; ++j) {
                const int r = row0 + wr + mi * 16 + kg * 4 + j;
                if (r < n) {
                    const int c = cbase + wc + ni * 16 + lr;
                    if (left)
                        Cl[(size_t)r * FO + c] = f2b(acc[mi][ni][j]);
                    else
                        Cr[(size_t)r * FO + c] = acc[mi][ni][j];
                }
            }
}

// ---- CSR build ----
__global__ void deg_count_kernel(const int* __restrict__ ei, int* __restrict__ deg) {
    const int e = blockIdx.x * 256 + threadIdx.x;
    if (e < N_EDGES) atomicAdd(&deg[ei[N_EDGES + e]], 1);
}

__global__ __launch_bounds__(256) void scanA_kernel(const int* __restrict__ deg,
                                                    int* __restrict__ rowp,
                                                    int* __restrict__ bsum) {
    const int t = threadIdx.x, b = blockIdx.x;
    const int i0 = b * 1024 + t * 4;
    int4 d = make_int4(0, 0, 0, 0);
    if (i0 + 3 < N_NODES) d = *(const int4*)(deg + i0);
    else {
        if (i0 + 0 < N_NODES) d.x = deg[i0 + 0];
        if (i0 + 1 < N_NODES) d.y = deg[i0 + 1];
        if (i0 + 2 < N_NODES) d.z = deg[i0 + 2];
    }
    const int tsum = d.x + d.y + d.z + d.w;
    int inc = tsum;
    const int lane = t & 63, wave = t >> 6;
#pragma unroll
    for (int o = 1; o < 64; o <<= 1) {
        int v = __shfl_up(inc, o, 64);
        if (lane >= o) inc += v;
    }
    __shared__ int wsum[4];
    if (lane == 63) wsum[wave] = inc;
    __syncthreads();
    int wbase = 0;
#pragma unroll
    for (int ww = 0; ww < 4; ++ww)
        if (ww < wave) wbase += wsum[ww];
    const int texcl = wbase + inc - tsum;
    int4 o4;
    o4.x = texcl;
    o4.y = o4.x + d.x;
    o4.z = o4.y + d.y;
    o4.w = o4.z + d.z;
    if (i0 + 3 < N_NODES) *(int4*)(rowp + i0) = o4;
    else {
        if (i0 + 0 < N_NODES) rowp[i0 + 0] = o4.x;
        if (i0 + 1 < N_NODES) rowp[i0 + 1] = o4.y;
        if (i0 + 2 < N_NODES) rowp[i0 + 2] = o4.z;
    }
    if (t == 255) bsum[b] = wbase + inc;
}

__global__ __launch_bounds__(256) void scanC_kernel(const int* __restrict__ bsum,
                                                    int* __restrict__ rowp) {
    const int t = threadIdx.x, b = blockIdx.x;
    __shared__ int base_s;
    if (t < 64) {
        int v = (t < b) ? bsum[t] : 0;
#pragma unroll
        for (int o = 32; o; o >>= 1) v += __shfl_xor(v, o, 64);
        if (t == 0) base_s = v;
    }
    __syncthreads();
    const int base = base_s;
    const int i0 = b * 1024 + t * 4;
    if (base != 0) {
        if (i0 + 3 < N_NODES) {
            int4 v = *(int4*)(rowp + i0);
            v.x += base; v.y += base; v.z += base; v.w += base;
            *(int4*)(rowp + i0) = v;
        } else {
            if (i0 + 0 < N_NODES) rowp[i0 + 0] += base;
            if (i0 + 1 < N_NODES) rowp[i0 + 1] += base;
            if (i0 + 2 < N_NODES) rowp[i0 + 2] += base;
        }
    }
    if (b == 0 && t == 0) rowp[N_NODES] = N_EDGES;
}

__global__ void csr_fill_kernel(const int* __restrict__ ei, const int* __restrict__ rowp,
                                int* __restrict__ cursor, int* __restrict__ csr_src) {
    const int e = blockIdx.x * 256 + threadIdx.x;
    if (e >= N_EDGES) return;
    const int d = ei[N_EDGES + e];
    const int pos = atomicAdd(&cursor[d], 1);
    csr_src[rowp[d] + pos] = ei[e];
}

// ---- online-softmax stream update with defer-max (THR=8) ----
template <int VEC>
__device__ __forceinline__ void sm_upd(float& m, float& s, float* acc, float p,
                                       const float* l) {
    if (p > m + 8.f) {               // wave-uniform; rare after warmup (defer-max)
        const float sc = __expf(m - p);  // exp(-inf)=0 handles first edge
        s = s * sc + 1.f;
#pragma unroll
        for (int k = 0; k < VEC; ++k) acc[k] = acc[k] * sc + l[k];
        m = p;
    } else {
        const float w = __expf(p - m);
        s += w;
#pragma unroll
        for (int k = 0; k < VEC; ++k) acc[k] += w * l[k];
    }
}

// ---- fused GATv2 edge phase: per-dst wave, dual-stream online softmax ----
template <int FO, int VEC>
__global__ __launch_bounds__(256) void gat_edge_kernel(
    const int* __restrict__ rowp, const int* __restrict__ csr_src,
    const ushort* __restrict__ xlb, const float* __restrict__ xr,
    const float* __restrict__ att, const float* __restrict__ bias,
    float* __restrict__ outf, ushort* __restrict__ outb, int do_relu) {
    const int d = blockIdx.x * 4 + (threadIdx.x >> 6);
    const int lane = threadIdx.x & 63;
    if (d >= N_NODES) return;
    const int co = lane * VEC;

    float a[VEC], r[VEC];
    if constexpr (VEC == 4) {
        float4 t4 = *(const float4*)(att + co);
        a[0] = t4.x; a[1] = t4.y; a[2] = t4.z; a[3] = t4.w;
        t4 = *(const float4*)(xr + (size_t)d * FO + co);
        r[0] = t4.x; r[1] = t4.y; r[2] = t4.z; r[3] = t4.w;
    } else {
        float2 t2 = *(const float2*)(att + co);
        a[0] = t2.x; a[1] = t2.y;
        t2 = *(const float2*)(xr + (size_t)d * FO + co);
        r[0] = t2.x; r[1] = t2.y;
    }

    const int jb = rowp[d], je = rowp[d + 1];
    float m0 = -INFINITY, s0 = 0.f, m1 = -INFINITY, s1 = 0.f;
    float acc0[VEC] = {}, acc1[VEC] = {};

    int j = jb;
    for (; j + 1 < je; j += 2) {
        const int src0 = csr_src[j];
        const int src1 = csr_src[j + 1];
        float l0[VEC], l1[VEC];
        if constexpr (VEC == 4) {
            ushort4 t0 = *(const ushort4*)(xlb + (size_t)src0 * FO + co);
            ushort4 t1 = *(const ushort4*)(xlb + (size_t)src1 * FO + co);
            l0[0] = b2f(t0.x); l0[1] = b2f(t0.y); l0[2] = b2f(t0.z); l0[3] = b2f(t0.w);
            l1[0] = b2f(t1.x); l1[1] = b2f(t1.y); l1[2] = b2f(t1.z); l1[3] = b2f(t1.w);
        } else {
            ushort2 t0 = *(const ushort2*)(xlb + (size_t)src0 * FO + co);
            ushort2 t1 = *(const ushort2*)(xlb + (size_t)src1 * FO + co);
            l0[0] = b2f(t0.x); l0[1] = b2f(t0.y);
            l1[0] = b2f(t1.x); l1[1] = b2f(t1.y);
        }
        float p0 = 0.f, p1 = 0.f;
#pragma unroll
        for (int k = 0; k < VEC; ++k) {
            float z0 = l0[k] + r[k];
            float z1 = l1[k] + r[k];
            z0 = z0 > 0.f ? z0 : NEG_SLOPE * z0;
            z1 = z1 > 0.f ? z1 : NEG_SLOPE * z1;
            p0 += z0 * a[k];
            p1 += z1 * a[k];
        }
#pragma unroll
        for (int o = 32; o; o >>= 1) {
            p0 += __shfl_xor(p0, o, 64);
            p1 += __shfl_xor(p1, o, 64);
        }
        sm_upd<VEC>(m0, s0, acc0, p0, l0);
        sm_upd<VEC>(m1, s1, acc1, p1, l1);
    }
    if (j < je) {
        const int src0 = csr_src[j];
        float l0[VEC];
        if constexpr (VEC == 4) {
            ushort4 t0 = *(const ushort4*)(xlb + (size_t)src0 * FO + co);
            l0[0] = b2f(t0.x); l0[1] = b2f(t0.y); l0[2] = b2f(t0.z); l0[3] = b2f(t0.w);
        } else {
            ushort2 t0 = *(const ushort2*)(xlb + (size_t)src0 * FO + co);
            l0[0] = b2f(t0.x); l0[1] = b2f(t0.y);
        }
        float p0 = 0.f;
#pragma unroll
        for (int k = 0; k < VEC; ++k) {
            float z0 = l0[k] + r[k];
            z0 = z0 > 0.f ? z0 : NEG_SLOPE * z0;
            p0 += z0 * a[k];
        }
#pragma unroll
        for (int o = 32; o; o >>= 1) p0 += __shfl_xor(p0, o, 64);
        sm_upd<VEC>(m0, s0, acc0, p0, l0);
    }

    // merge the two streams (guard deg==0 to avoid (-inf)-(-inf) NaN)
    float s, acc[VEC];
    if (je > jb) {
        const float M = fmaxf(m0, m1);
        const float sc0 = __expf(m0 - M);
        const float sc1 = __expf(m1 - M);
        s = s0 * sc0 + s1 * sc1;
#pragma unroll
        for (int k = 0; k < VEC; ++k) acc[k] = acc0[k] * sc0 + acc1[k] * sc1;
    } else {
        s = 0.f;
#pragma unroll
        for (int k = 0; k < VEC; ++k) acc[k] = 0.f;
    }

    const float inv = 1.f / (s + 1e-16f);
#pragma unroll
    for (int k = 0; k < VEC; ++k) {
        float v = acc[k] * inv + bias[co + k];
        if (do_relu) v = fmaxf(v, 0.f);
        acc[k] = v;
    }
    if (outf) {
        if constexpr (VEC == 4)
            *(float4*)(outf + (size_t)d * FO + co) = make_float4(acc[0], acc[1], acc[2], acc[3]);
        else
            *(float2*)(outf + (size_t)d * FO + co) = make_float2(acc[0], acc[1]);
    }
    if (outb) {
        if constexpr (VEC == 4) {
            ushort4 o; o.x = f2b(acc[0]); o.y = f2b(acc[1]); o.z = f2b(acc[2]); o.w = f2b(acc[3]);
            *(ushort4*)(outb + (size_t)d * FO + co) = o;
        } else {
            ushort2 o; o.x = f2b(acc[0]); o.y = f2b(acc[1]);
            *(ushort2*)(outb + (size_t)d * FO + co) = o;
        }
    }
}

// ---- graph boundaries from sorted batch ----
__global__ void gstart_kernel(const int* __restrict__ batch, int* __restrict__ gstart) {
    const int i = blockIdx.x * 256 + threadIdx.x;
    if (i >= N_NODES) return;
    const int b = batch[i];
    if (i == 0) {
        for (int g = 0; g <= b; ++g) gstart[g] = 0;
    } else {
        const int pb = batch[i - 1];
        for (int g = pb + 1; g <= b; ++g) gstart[g] = i;
    }
    if (i == N_NODES - 1) {
        for (int g = b + 1; g <= N_GRAPHS; ++g) gstart[g] = N_NODES;
    }
}

// ---- per-graph pool: one block per graph, zero atomics ----
__global__ __launch_bounds__(128) void pool2_kernel(const float* __restrict__ h,
                                                    const int* __restrict__ gstart,
                                                    float* __restrict__ gsum,
                                                    float* __restrict__ gcnt) {
    const int g = blockIdx.x, t = threadIdx.x;
    const int b = gstart[g], e = gstart[g + 1];
    float s = 0.f;
    for (int i = b; i < e; ++i) s += h[(size_t)i * 128 + t];
    gsum[g * 128 + t] = s;
    if (t == 0) gcnt[g] = (float)(e - b);
}

// ---- fused MLP head ----
__global__ __launch_bounds__(128) void mlp_kernel(
    const float* __restrict__ gsum, const float* __restrict__ gcnt,
    const float* __restrict__ W1, const float* __restrict__ b1,
    const float* __restrict__ W2, const float* __restrict__ b2,
    const float* __restrict__ W3, const float* __restrict__ b3,
    const float* __restrict__ bng_g, const float* __restrict__ bng_b,
    const float* __restrict__ bng_m, const float* __restrict__ bng_v,
    const float* __restrict__ bn1_g, const float* __restrict__ bn1_b,
    const float* __restrict__ bn1_m, const float* __restrict__ bn1_v,
    const float* __restrict__ bn2_g, const float* __restrict__ bn2_b,
    const float* __restrict__ bn2_m, const float* __restrict__ bn2_v,
    float* __restrict__ out) {
    __shared__ float s0[128], s1[128], s2[64];
    const int g = blockIdx.x, t = threadIdx.x;
    const float cnt = fmaxf(gcnt[g], 1.f);
    float v = gsum[g * 128 + t] / cnt;
    v = (v - bng_m[t]) * rsqrtf(bng_v[t] + BN_EPS) * bng_g[t] + bng_b[t];
    s0[t] = v;
    __syncthreads();
    float a1 = b1[t];
    for (int i = 0; i < 128; ++i) a1 += s0[i] * W1[i * 128 + t];
    a1 = fmaxf(a1, 0.f);
    a1 = (a1 - bn1_m[t]) * rsqrtf(bn1_v[t] + BN_EPS) * bn1_g[t] + bn1_b[t];
    s1[t] = a1;
    __syncthreads();
    if (t < 64) {
        float a2 = b2[t];
        for (int i = 0; i < 128; ++i) a2 += s1[i] * W2[i * 64 + t];
        a2 = fmaxf(a2, 0.f);
        a2 = (a2 - bn2_m[t]) * rsqrtf(bn2_v[t] + BN_EPS) * bn2_g[t] + bn2_b[t];
        s2[t] = a2;
    }
    __syncthreads();
    if (t < 2) {
        float a3 = b3[t];
        for (int i = 0; i < 64; ++i) a3 += s2[i] * W3[i * 2 + t];
        out[g * 2 + t] = fmaxf(a3, 0.f);
    }
}

extern "C" void kernel_launch(void* const* d_in, const int* in_sizes, int n_in,
                              void* d_out, int out_size, void* d_ws, size_t ws_size,
                              hipStream_t stream) {
    const float* x = (const float*)d_in[0];
    const int* ei = (const int*)d_in[1];
    const int* batch = (const int*)d_in[2];
    const float* Wl1 = (const float*)d_in[3];
    const float* Wr1 = (const float*)d_in[4];
    const float* att1 = (const float*)d_in[5];
    const float* b1 = (const float*)d_in[6];
    const float* Wl2 = (const float*)d_in[7];
    const float* Wr2 = (const float*)d_in[8];
    const float* att2 = (const float*)d_in[9];
    const float* b2 = (const float*)d_in[10];
    const float* Wl3 = (const float*)d_in[11];
    const float* Wr3 = (const float*)d_in[12];
    const float* att3 = (const float*)d_in[13];
    const float* b3 = (const float*)d_in[14];
    const float* Wlin1 = (const float*)d_in[15];
    const float* blin1 = (const float*)d_in[16];
    const float* Wlin2 = (const float*)d_in[17];
    const float* blin2 = (const float*)d_in[18];
    const float* Wlin3 = (const float*)d_in[19];
    const float* blin3 = (const float*)d_in[20];
    const float* bng_g = (const float*)d_in[21];
    const float* bng_b = (const float*)d_in[22];
    const float* bng_m = (const float*)d_in[23];
    const float* bng_v = (const float*)d_in[24];
    const float* bn1_g = (const float*)d_in[25];
    const float* bn1_b = (const float*)d_in[26];
    const float* bn1_m = (const float*)d_in[27];
    const float* bn1_v = (const float*)d_in[28];
    const float* bn2_g = (const float*)d_in[29];
    const float* bn2_b = (const float*)d_in[30];
    const float* bn2_m = (const float*)d_in[31];
    const float* bn2_v = (const float*)d_in[32];

    float* ws = (float*)d_ws;
    ushort* xlb = (ushort*)ws;                           // bf16 xl (N*256 max)
    float* xr = (float*)(xlb + (size_t)N_NODES * 256);   // fp32 xr (N*256 max)
    float* h3 = xr + (size_t)N_NODES * 256;              // fp32 L3 out (N*128)
    ushort* hbf = (ushort*)(h3 + (size_t)N_NODES * 128); // bf16 layer input (N*256)
    ushort* wt1 = hbf + (size_t)N_NODES * 256;           // 256*128
    ushort* wt2 = wt1 + 256 * 128;                       // 512*128
    ushort* wt3 = wt2 + 512 * 128;                       // 256*256
    int* deg = (int*)(wt3 + 256 * 256);                  // N
    int* cursor = deg + N_NODES;                         // N
    int* rowp = cursor + N_NODES;                        // N+1
    int* csr_src = rowp + N_NODES + 1;                   // E
    int* gstart = csr_src + N_EDGES;                     // G+1
    int* bsum = gstart + N_GRAPHS + 1;                   // SCAN_BLOCKS
    float* gsum = (float*)(bsum + SCAN_BLOCKS);          // G*128
    float* gcnt = gsum + (size_t)N_GRAPHS * 128;         // G

    const int eb = (N_EDGES + 255) / 256;

    // ---- CSR build (hierarchical scan) ----
    hipMemsetAsync(deg, 0, (size_t)N_NODES * 2 * 4, stream);  // deg + cursor
    deg_count_kernel<<<eb, 256, 0, stream>>>(ei, deg);
    scanA_kernel<<<SCAN_BLOCKS, 256, 0, stream>>>(deg, rowp, bsum);
    scanC_kernel<<<SCAN_BLOCKS, 256, 0, stream>>>(bsum, rowp);
    csr_fill_kernel<<<eb, 256, 0, stream>>>(ei, rowp, cursor, csr_src);
    gstart_kernel<<<(N_NODES + 255) / 256, 256, 0, stream>>>(batch, gstart);

    // ---- weights + x -> bf16 ----
    wcvt_all_kernel<<<640, 256, 0, stream>>>(Wl1, Wr1, Wl2, Wr2, Wl3, Wr3, wt1, wt2, wt3);
    cvt_kernel<<<(N_NODES * 128 / 4 + 255) / 256, 256, 0, stream>>>(
        x, hbf, N_NODES * 128 / 4);

    const int nb = (N_NODES + 3) / 4;
    const int gx = (N_NODES + 127) / 128;

    // L1: K=128, FO=128
    gemm_bf16_kernel<<<dim3(gx, 2), 256, 0, stream>>>(hbf, wt1, xlb, xr, N_NODES, 128, 128);
    gat_edge_kernel<128, 2><<<nb, 256, 0, stream>>>(rowp, csr_src, xlb, xr,
                                                    att1, b1, nullptr, hbf, 1);
    // L2: K=128, FO=256
    gemm_bf16_kernel<<<dim3(gx, 4), 256, 0, stream>>>(hbf, wt2, xlb, xr, N_NODES, 128, 256);
    gat_edge_kernel<256, 4><<<nb, 256, 0, stream>>>(rowp, csr_src, xlb, xr,
                                                    att2, b2, nullptr, hbf, 1);
    // L3: K=256, FO=128 -> h3 fp32
    gemm_bf16_kernel<<<dim3(gx, 2), 256, 0, stream>>>(hbf, wt3, xlb, xr, N_NODES, 256, 128);
    gat_edge_kernel<128, 2><<<nb, 256, 0, stream>>>(rowp, csr_src, xlb, xr,
                                                    att3, b3, h3, nullptr, 0);

    // pool (no atomics)
    pool2_kernel<<<N_GRAPHS, 128, 0, stream>>>(h3, gstart, gsum, gcnt);

    // MLP head
    mlp_kernel<<<N_GRAPHS, 128, 0, stream>>>(
        gsum, gcnt, Wlin1, blin1, Wlin2, blin2, Wlin3, blin3,
        bng_g, bng_b, bng_m, bng_v, bn1_g, bn1_b, bn1_m, bn1_v,
        bn2_g, bn2_b, bn2_m, bn2_v, (float*)d_out);
}

// Round 7
// 317.338 us; speedup vs baseline: 8.9601x; 1.0120x over previous
//
#include <hip/hip_runtime.h>
#include <math.h>

#define N_NODES 50000
#define N_EDGES 400000
#define N_GRAPHS 512
#define NEG_SLOPE 0.2f
#define BN_EPS 1e-5f
#define SCAN_BLOCKS 49   // ceil(50000/1024)

// leaky(z,0.2) = 0.6z + 0.4|z|; fold 1/ln2 so exp() becomes exp2()
#define C6 0.8656170245333781f   // 0.6 / ln2
#define C4 0.5770780163555854f   // 0.4 / ln2
#define THR_LOG2 11.541560327111708f  // 8 / ln2

typedef __attribute__((ext_vector_type(8))) short bf16x8;
typedef __attribute__((ext_vector_type(4))) float f32x4;

// ---- fp32 -> bf16 (round-to-nearest-even) ----
__device__ __forceinline__ ushort f2b(float f) {
    unsigned u = __float_as_uint(f);
    unsigned r = (u + 0x7fffu + ((u >> 16) & 1u)) >> 16;
    return (ushort)r;
}
__device__ __forceinline__ float b2f(ushort u) {
    return __uint_as_float((unsigned)u << 16);
}

// ---- activation fp32 -> bf16, vectorized x4 ----
__global__ void cvt_kernel(const float* __restrict__ in, ushort* __restrict__ out,
                           int total4) {
    const int i = blockIdx.x * 256 + threadIdx.x;
    if (i >= total4) return;
    float4 v = *(const float4*)(in + (size_t)i * 4);
    ushort4 o;
    o.x = f2b(v.x); o.y = f2b(v.y); o.z = f2b(v.z); o.w = f2b(v.w);
    *(ushort4*)(out + (size_t)i * 4) = o;
}

// ---- fused weight convert+transpose for all 3 layers ----
__global__ void wcvt_all_kernel(const float* __restrict__ Wl1, const float* __restrict__ Wr1,
                                const float* __restrict__ Wl2, const float* __restrict__ Wr2,
                                const float* __restrict__ Wl3, const float* __restrict__ Wr3,
                                ushort* __restrict__ wt1, ushort* __restrict__ wt2,
                                ushort* __restrict__ wt3) {
    const int i = blockIdx.x * 256 + threadIdx.x;
    if (i < 32768) {
        const int m = i >> 7, k = i & 127;
        const float v = (m < 128) ? Wl1[k * 128 + m] : Wr1[k * 128 + (m - 128)];
        wt1[i] = f2b(v);
    } else if (i < 98304) {
        const int j = i - 32768;
        const int m = j >> 7, k = j & 127;
        const float v = (m < 256) ? Wl2[k * 256 + m] : Wr2[k * 256 + (m - 256)];
        wt2[j] = f2b(v);
    } else if (i < 163840) {
        const int j = i - 98304;
        const int m = j >> 8, k = j & 255;
        const float v = (m < 128) ? Wl3[k * 128 + m] : Wr3[k * 128 + (m - 128)];
        wt3[j] = f2b(v);
    }
}

// ---- bf16 MFMA GEMM, combined [xl|xr] output ----
__global__ __launch_bounds__(256) void gemm_bf16_kernel(
    const ushort* __restrict__ A, const ushort* __restrict__ Bt,
    ushort* __restrict__ Cl, float* __restrict__ Cr, int n, int K, int FO) {
    __shared__ ushort As[128][40];
    __shared__ ushort Bs[128][40];
    const int tid = threadIdx.x;
    const int row0 = blockIdx.x * 128;
    const int col0 = blockIdx.y * 128;
    const int w = tid >> 6, lane = tid & 63;
    const int wr = (w >> 1) * 64, wc = (w & 1) * 64;
    const int lr = lane & 15, kg = lane >> 4;

    const int srow = tid >> 1, shalf = tid & 1;

    f32x4 acc[4][4];
#pragma unroll
    for (int i = 0; i < 4; ++i)
#pragma unroll
        for (int j = 0; j < 4; ++j) acc[i][j] = (f32x4){0.f, 0.f, 0.f, 0.f};

    for (int k0 = 0; k0 < K; k0 += 32) {
        {
            const int gr = row0 + srow;
            uint4 v0 = make_uint4(0, 0, 0, 0), v1 = v0;
            if (gr < n) {
                const uint4* p = (const uint4*)(A + (size_t)gr * K + k0) + shalf * 2;
                v0 = p[0]; v1 = p[1];
            }
            uint4* d = (uint4*)&As[srow][shalf * 16];
            d[0] = v0; d[1] = v1;
            const int gb = col0 + srow;
            const uint4* p = (const uint4*)(Bt + (size_t)gb * K + k0) + shalf * 2;
            uint4* db = (uint4*)&Bs[srow][shalf * 16];
            db[0] = p[0]; db[1] = p[1];
        }
        __syncthreads();
        bf16x8 af[4], bfr[4];
#pragma unroll
        for (int mi = 0; mi < 4; ++mi)
            af[mi] = *(const bf16x8*)&As[wr + mi * 16 + lr][kg * 8];
#pragma unroll
        for (int ni = 0; ni < 4; ++ni)
            bfr[ni] = *(const bf16x8*)&Bs[wc + ni * 16 + lr][kg * 8];
#pragma unroll
        for (int mi = 0; mi < 4; ++mi)
#pragma unroll
            for (int ni = 0; ni < 4; ++ni)
                acc[mi][ni] = __builtin_amdgcn_mfma_f32_16x16x32_bf16(
                    af[mi], bfr[ni], acc[mi][ni], 0, 0, 0);
        __syncthreads();
    }
    const bool left = (col0 < FO);
    const int cbase = left ? col0 : col0 - FO;
#pragma unroll
    for (int mi = 0; mi < 4; ++mi)
#pragma unroll
        for (int ni = 0; ni < 4; ++ni)
#pragma unroll
            for (int j = 0; j < 4; ++j) {
                const int r = row0 + wr + mi * 16 + kg * 4 + j;
                if (r < n) {
                    const int c = cbase + wc + ni * 16 + lr;
                    if (left)
                        Cl[(size_t)r * FO + c] = f2b(acc[mi][ni][j]);
                    else
                        Cr[(size_t)r * FO + c] = acc[mi][ni][j];
                }
            }
}

// ---- CSR build ----
__global__ void deg_count_kernel(const int* __restrict__ ei, int* __restrict__ deg) {
    const int e = blockIdx.x * 256 + threadIdx.x;
    if (e < N_EDGES) atomicAdd(&deg[ei[N_EDGES + e]], 1);
}

__global__ __launch_bounds__(256) void scanA_kernel(const int* __restrict__ deg,
                                                    int* __restrict__ rowp,
                                                    int* __restrict__ bsum) {
    const int t = threadIdx.x, b = blockIdx.x;
    const int i0 = b * 1024 + t * 4;
    int4 d = make_int4(0, 0, 0, 0);
    if (i0 + 3 < N_NODES) d = *(const int4*)(deg + i0);
    else {
        if (i0 + 0 < N_NODES) d.x = deg[i0 + 0];
        if (i0 + 1 < N_NODES) d.y = deg[i0 + 1];
        if (i0 + 2 < N_NODES) d.z = deg[i0 + 2];
    }
    const int tsum = d.x + d.y + d.z + d.w;
    int inc = tsum;
    const int lane = t & 63, wave = t >> 6;
#pragma unroll
    for (int o = 1; o < 64; o <<= 1) {
        int v = __shfl_up(inc, o, 64);
        if (lane >= o) inc += v;
    }
    __shared__ int wsum[4];
    if (lane == 63) wsum[wave] = inc;
    __syncthreads();
    int wbase = 0;
#pragma unroll
    for (int ww = 0; ww < 4; ++ww)
        if (ww < wave) wbase += wsum[ww];
    const int texcl = wbase + inc - tsum;
    int4 o4;
    o4.x = texcl;
    o4.y = o4.x + d.x;
    o4.z = o4.y + d.y;
    o4.w = o4.z + d.z;
    if (i0 + 3 < N_NODES) *(int4*)(rowp + i0) = o4;
    else {
        if (i0 + 0 < N_NODES) rowp[i0 + 0] = o4.x;
        if (i0 + 1 < N_NODES) rowp[i0 + 1] = o4.y;
        if (i0 + 2 < N_NODES) rowp[i0 + 2] = o4.z;
    }
    if (t == 255) bsum[b] = wbase + inc;
}

__global__ __launch_bounds__(256) void scanC_kernel(const int* __restrict__ bsum,
                                                    int* __restrict__ rowp) {
    const int t = threadIdx.x, b = blockIdx.x;
    __shared__ int base_s;
    if (t < 64) {
        int v = (t < b) ? bsum[t] : 0;
#pragma unroll
        for (int o = 32; o; o >>= 1) v += __shfl_xor(v, o, 64);
        if (t == 0) base_s = v;
    }
    __syncthreads();
    const int base = base_s;
    const int i0 = b * 1024 + t * 4;
    if (base != 0) {
        if (i0 + 3 < N_NODES) {
            int4 v = *(int4*)(rowp + i0);
            v.x += base; v.y += base; v.z += base; v.w += base;
            *(int4*)(rowp + i0) = v;
        } else {
            if (i0 + 0 < N_NODES) rowp[i0 + 0] += base;
            if (i0 + 1 < N_NODES) rowp[i0 + 1] += base;
            if (i0 + 2 < N_NODES) rowp[i0 + 2] += base;
        }
    }
    if (b == 0 && t == 0) rowp[N_NODES] = N_EDGES;
}

__global__ void csr_fill_kernel(const int* __restrict__ ei, const int* __restrict__ rowp,
                                int* __restrict__ cursor, int* __restrict__ csr_src) {
    const int e = blockIdx.x * 256 + threadIdx.x;
    if (e >= N_EDGES) return;
    const int d = ei[N_EDGES + e];
    const int pos = atomicAdd(&cursor[d], 1);
    csr_src[rowp[d] + pos] = ei[e];
}

// ---- online-softmax stream update, log2 domain, defer-max ----
template <int VEC>
__device__ __forceinline__ void sm_upd(float& m, float& s, float* acc, float p,
                                       const float* l) {
    if (p > m + THR_LOG2) {          // wave-uniform; rare after warmup (defer-max)
        const float sc = __builtin_amdgcn_exp2f(m - p);  // exp2(-inf)=0: first edge ok
        s = s * sc + 1.f;
#pragma unroll
        for (int k = 0; k < VEC; ++k) acc[k] = acc[k] * sc + l[k];
        m = p;
    } else {
        const float w = __builtin_amdgcn_exp2f(p - m);
        s += w;
#pragma unroll
        for (int k = 0; k < VEC; ++k) acc[k] += w * l[k];
    }
}

// ---- fused GATv2 edge phase: per-dst wave, dual-stream, log2-domain softmax ----
template <int FO, int VEC>
__global__ __launch_bounds__(256) void gat_edge_kernel(
    const int* __restrict__ rowp, const int* __restrict__ csr_src,
    const ushort* __restrict__ xlb, const float* __restrict__ xr,
    const float* __restrict__ att, const float* __restrict__ bias,
    float* __restrict__ outf, ushort* __restrict__ outb, int do_relu) {
    const int d = blockIdx.x * 4 + (threadIdx.x >> 6);
    const int lane = threadIdx.x & 63;
    if (d >= N_NODES) return;
    const int co = lane * VEC;

    // a6 = 0.6*att/ln2, a4 = 0.4*att/ln2  (leaky(z)=0.6z+0.4|z|, exp->exp2)
    float a6[VEC], a4[VEC], r[VEC];
    if constexpr (VEC == 4) {
        float4 t4 = *(const float4*)(att + co);
        a6[0] = C6 * t4.x; a6[1] = C6 * t4.y; a6[2] = C6 * t4.z; a6[3] = C6 * t4.w;
        a4[0] = C4 * t4.x; a4[1] = C4 * t4.y; a4[2] = C4 * t4.z; a4[3] = C4 * t4.w;
        t4 = *(const float4*)(xr + (size_t)d * FO + co);
        r[0] = t4.x; r[1] = t4.y; r[2] = t4.z; r[3] = t4.w;
    } else {
        float2 t2 = *(const float2*)(att + co);
        a6[0] = C6 * t2.x; a6[1] = C6 * t2.y;
        a4[0] = C4 * t2.x; a4[1] = C4 * t2.y;
        t2 = *(const float2*)(xr + (size_t)d * FO + co);
        r[0] = t2.x; r[1] = t2.y;
    }

    const int jb = rowp[d], je = rowp[d + 1];
    float m0 = -INFINITY, s0 = 0.f, m1 = -INFINITY, s1 = 0.f;
    float acc0[VEC] = {}, acc1[VEC] = {};

    int j = jb;
    for (; j + 1 < je; j += 2) {
        const int src0 = csr_src[j];
        const int src1 = csr_src[j + 1];
        float l0[VEC], l1[VEC];
        if constexpr (VEC == 4) {
            ushort4 t0 = *(const ushort4*)(xlb + (size_t)src0 * FO + co);
            ushort4 t1 = *(const ushort4*)(xlb + (size_t)src1 * FO + co);
            l0[0] = b2f(t0.x); l0[1] = b2f(t0.y); l0[2] = b2f(t0.z); l0[3] = b2f(t0.w);
            l1[0] = b2f(t1.x); l1[1] = b2f(t1.y); l1[2] = b2f(t1.z); l1[3] = b2f(t1.w);
        } else {
            ushort2 t0 = *(const ushort2*)(xlb + (size_t)src0 * FO + co);
            ushort2 t1 = *(const ushort2*)(xlb + (size_t)src1 * FO + co);
            l0[0] = b2f(t0.x); l0[1] = b2f(t0.y);
            l1[0] = b2f(t1.x); l1[1] = b2f(t1.y);
        }
        float p0 = 0.f, p1 = 0.f;
#pragma unroll
        for (int k = 0; k < VEC; ++k) {
            const float z0 = l0[k] + r[k];
            const float z1 = l1[k] + r[k];
            p0 = fmaf(a6[k], z0, p0); p0 = fmaf(a4[k], fabsf(z0), p0);
            p1 = fmaf(a6[k], z1, p1); p1 = fmaf(a4[k], fabsf(z1), p1);
        }
#pragma unroll
        for (int o = 32; o; o >>= 1) {
            p0 += __shfl_xor(p0, o, 64);
            p1 += __shfl_xor(p1, o, 64);
        }
        sm_upd<VEC>(m0, s0, acc0, p0, l0);
        sm_upd<VEC>(m1, s1, acc1, p1, l1);
    }
    if (j < je) {
        const int src0 = csr_src[j];
        float l0[VEC];
        if constexpr (VEC == 4) {
            ushort4 t0 = *(const ushort4*)(xlb + (size_t)src0 * FO + co);
            l0[0] = b2f(t0.x); l0[1] = b2f(t0.y); l0[2] = b2f(t0.z); l0[3] = b2f(t0.w);
        } else {
            ushort2 t0 = *(const ushort2*)(xlb + (size_t)src0 * FO + co);
            l0[0] = b2f(t0.x); l0[1] = b2f(t0.y);
        }
        float p0 = 0.f;
#pragma unroll
        for (int k = 0; k < VEC; ++k) {
            const float z0 = l0[k] + r[k];
            p0 = fmaf(a6[k], z0, p0); p0 = fmaf(a4[k], fabsf(z0), p0);
        }
#pragma unroll
        for (int o = 32; o; o >>= 1) p0 += __shfl_xor(p0, o, 64);
        sm_upd<VEC>(m0, s0, acc0, p0, l0);
    }

    // merge the two streams (guard deg==0 to avoid (-inf)-(-inf) NaN)
    float s, acc[VEC];
    if (je > jb) {
        const float M = fmaxf(m0, m1);
        const float sc0 = __builtin_amdgcn_exp2f(m0 - M);
        const float sc1 = __builtin_amdgcn_exp2f(m1 - M);
        s = s0 * sc0 + s1 * sc1;
#pragma unroll
        for (int k = 0; k < VEC; ++k) acc[k] = acc0[k] * sc0 + acc1[k] * sc1;
    } else {
        s = 0.f;
#pragma unroll
        for (int k = 0; k < VEC; ++k) acc[k] = 0.f;
    }

    const float inv = 1.f / (s + 1e-16f);
#pragma unroll
    for (int k = 0; k < VEC; ++k) {
        float v = acc[k] * inv + bias[co + k];
        if (do_relu) v = fmaxf(v, 0.f);
        acc[k] = v;
    }
    if (outf) {
        if constexpr (VEC == 4)
            *(float4*)(outf + (size_t)d * FO + co) = make_float4(acc[0], acc[1], acc[2], acc[3]);
        else
            *(float2*)(outf + (size_t)d * FO + co) = make_float2(acc[0], acc[1]);
    }
    if (outb) {
        if constexpr (VEC == 4) {
            ushort4 o; o.x = f2b(acc[0]); o.y = f2b(acc[1]); o.z = f2b(acc[2]); o.w = f2b(acc[3]);
            *(ushort4*)(outb + (size_t)d * FO + co) = o;
        } else {
            ushort2 o; o.x = f2b(acc[0]); o.y = f2b(acc[1]);
            *(ushort2*)(outb + (size_t)d * FO + co) = o;
        }
    }
}

// ---- graph boundaries from sorted batch ----
__global__ void gstart_kernel(const int* __restrict__ batch, int* __restrict__ gstart) {
    const int i = blockIdx.x * 256 + threadIdx.x;
    if (i >= N_NODES) return;
    const int b = batch[i];
    if (i == 0) {
        for (int g = 0; g <= b; ++g) gstart[g] = 0;
    } else {
        const int pb = batch[i - 1];
        for (int g = pb + 1; g <= b; ++g) gstart[g] = i;
    }
    if (i == N_NODES - 1) {
        for (int g = b + 1; g <= N_GRAPHS; ++g) gstart[g] = N_NODES;
    }
}

// ---- per-graph pool: one block per graph, zero atomics ----
__global__ __launch_bounds__(128) void pool2_kernel(const float* __restrict__ h,
                                                    const int* __restrict__ gstart,
                                                    float* __restrict__ gsum,
                                                    float* __restrict__ gcnt) {
    const int g = blockIdx.x, t = threadIdx.x;
    const int b = gstart[g], e = gstart[g + 1];
    float s = 0.f;
    for (int i = b; i < e; ++i) s += h[(size_t)i * 128 + t];
    gsum[g * 128 + t] = s;
    if (t == 0) gcnt[g] = (float)(e - b);
}

// ---- fused MLP head ----
__global__ __launch_bounds__(128) void mlp_kernel(
    const float* __restrict__ gsum, const float* __restrict__ gcnt,
    const float* __restrict__ W1, const float* __restrict__ b1,
    const float* __restrict__ W2, const float* __restrict__ b2,
    const float* __restrict__ W3, const float* __restrict__ b3,
    const float* __restrict__ bng_g, const float* __restrict__ bng_b,
    const float* __restrict__ bng_m, const float* __restrict__ bng_v,
    const float* __restrict__ bn1_g, const float* __restrict__ bn1_b,
    const float* __restrict__ bn1_m, const float* __restrict__ bn1_v,
    const float* __restrict__ bn2_g, const float* __restrict__ bn2_b,
    const float* __restrict__ bn2_m, const float* __restrict__ bn2_v,
    float* __restrict__ out) {
    __shared__ float s0[128], s1[128], s2[64];
    const int g = blockIdx.x, t = threadIdx.x;
    const float cnt = fmaxf(gcnt[g], 1.f);
    float v = gsum[g * 128 + t] / cnt;
    v = (v - bng_m[t]) * rsqrtf(bng_v[t] + BN_EPS) * bng_g[t] + bng_b[t];
    s0[t] = v;
    __syncthreads();
    float a1 = b1[t];
    for (int i = 0; i < 128; ++i) a1 += s0[i] * W1[i * 128 + t];
    a1 = fmaxf(a1, 0.f);
    a1 = (a1 - bn1_m[t]) * rsqrtf(bn1_v[t] + BN_EPS) * bn1_g[t] + bn1_b[t];
    s1[t] = a1;
    __syncthreads();
    if (t < 64) {
        float a2 = b2[t];
        for (int i = 0; i < 128; ++i) a2 += s1[i] * W2[i * 64 + t];
        a2 = fmaxf(a2, 0.f);
        a2 = (a2 - bn2_m[t]) * rsqrtf(bn2_v[t] + BN_EPS) * bn2_g[t] + bn2_b[t];
        s2[t] = a2;
    }
    __syncthreads();
    if (t < 2) {
        float a3 = b3[t];
        for (int i = 0; i < 64; ++i) a3 += s2[i] * W3[i * 2 + t];
        out[g * 2 + t] = fmaxf(a3, 0.f);
    }
}

extern "C" void kernel_launch(void* const* d_in, const int* in_sizes, int n_in,
                              void* d_out, int out_size, void* d_ws, size_t ws_size,
                              hipStream_t stream) {
    const float* x = (const float*)d_in[0];
    const int* ei = (const int*)d_in[1];
    const int* batch = (const int*)d_in[2];
    const float* Wl1 = (const float*)d_in[3];
    const float* Wr1 = (const float*)d_in[4];
    const float* att1 = (const float*)d_in[5];
    const float* b1 = (const float*)d_in[6];
    const float* Wl2 = (const float*)d_in[7];
    const float* Wr2 = (const float*)d_in[8];
    const float* att2 = (const float*)d_in[9];
    const float* b2 = (const float*)d_in[10];
    const float* Wl3 = (const float*)d_in[11];
    const float* Wr3 = (const float*)d_in[12];
    const float* att3 = (const float*)d_in[13];
    const float* b3 = (const float*)d_in[14];
    const float* Wlin1 = (const float*)d_in[15];
    const float* blin1 = (const float*)d_in[16];
    const float* Wlin2 = (const float*)d_in[17];
    const float* blin2 = (const float*)d_in[18];
    const float* Wlin3 = (const float*)d_in[19];
    const float* blin3 = (const float*)d_in[20];
    const float* bng_g = (const float*)d_in[21];
    const float* bng_b = (const float*)d_in[22];
    const float* bng_m = (const float*)d_in[23];
    const float* bng_v = (const float*)d_in[24];
    const float* bn1_g = (const float*)d_in[25];
    const float* bn1_b = (const float*)d_in[26];
    const float* bn1_m = (const float*)d_in[27];
    const float* bn1_v = (const float*)d_in[28];
    const float* bn2_g = (const float*)d_in[29];
    const float* bn2_b = (const float*)d_in[30];
    const float* bn2_m = (const float*)d_in[31];
    const float* bn2_v = (const float*)d_in[32];

    float* ws = (float*)d_ws;
    ushort* xlb = (ushort*)ws;                           // bf16 xl (N*256 max)
    float* xr = (float*)(xlb + (size_t)N_NODES * 256);   // fp32 xr (N*256 max)
    float* h3 = xr + (size_t)N_NODES * 256;              // fp32 L3 out (N*128)
    ushort* hbf = (ushort*)(h3 + (size_t)N_NODES * 128); // bf16 layer input (N*256)
    ushort* wt1 = hbf + (size_t)N_NODES * 256;           // 256*128
    ushort* wt2 = wt1 + 256 * 128;                       // 512*128
    ushort* wt3 = wt2 + 512 * 128;                       // 256*256
    int* deg = (int*)(wt3 + 256 * 256);                  // N
    int* cursor = deg + N_NODES;                         // N
    int* rowp = cursor + N_NODES;                        // N+1
    int* csr_src = rowp + N_NODES + 1;                   // E
    int* gstart = csr_src + N_EDGES;                     // G+1
    int* bsum = gstart + N_GRAPHS + 1;                   // SCAN_BLOCKS
    float* gsum = (float*)(bsum + SCAN_BLOCKS);          // G*128
    float* gcnt = gsum + (size_t)N_GRAPHS * 128;         // G

    const int eb = (N_EDGES + 255) / 256;

    // ---- CSR build (hierarchical scan) ----
    hipMemsetAsync(deg, 0, (size_t)N_NODES * 2 * 4, stream);  // deg + cursor
    deg_count_kernel<<<eb, 256, 0, stream>>>(ei, deg);
    scanA_kernel<<<SCAN_BLOCKS, 256, 0, stream>>>(deg, rowp, bsum);
    scanC_kernel<<<SCAN_BLOCKS, 256, 0, stream>>>(bsum, rowp);
    csr_fill_kernel<<<eb, 256, 0, stream>>>(ei, rowp, cursor, csr_src);
    gstart_kernel<<<(N_NODES + 255) / 256, 256, 0, stream>>>(batch, gstart);

    // ---- weights + x -> bf16 ----
    wcvt_all_kernel<<<640, 256, 0, stream>>>(Wl1, Wr1, Wl2, Wr2, Wl3, Wr3, wt1, wt2, wt3);
    cvt_kernel<<<(N_NODES * 128 / 4 + 255) / 256, 256, 0, stream>>>(
        x, hbf, N_NODES * 128 / 4);

    const int nb = (N_NODES + 3) / 4;
    const int gx = (N_NODES + 127) / 128;

    // L1: K=128, FO=128
    gemm_bf16_kernel<<<dim3(gx, 2), 256, 0, stream>>>(hbf, wt1, xlb, xr, N_NODES, 128, 128);
    gat_edge_kernel<128, 2><<<nb, 256, 0, stream>>>(rowp, csr_src, xlb, xr,
                                                    att1, b1, nullptr, hbf, 1);
    // L2: K=128, FO=256
    gemm_bf16_kernel<<<dim3(gx, 4), 256, 0, stream>>>(hbf, wt2, xlb, xr, N_NODES, 128, 256);
    gat_edge_kernel<256, 4><<<nb, 256, 0, stream>>>(rowp, csr_src, xlb, xr,
                                                    att2, b2, nullptr, hbf, 1);
    // L3: K=256, FO=128 -> h3 fp32
    gemm_bf16_kernel<<<dim3(gx, 2), 256, 0, stream>>>(hbf, wt3, xlb, xr, N_NODES, 256, 128);
    gat_edge_kernel<128, 2><<<nb, 256, 0, stream>>>(rowp, csr_src, xlb, xr,
                                                    att3, b3, h3, nullptr, 0);

    // pool (no atomics)
    pool2_kernel<<<N_GRAPHS, 128, 0, stream>>>(h3, gstart, gsum, gcnt);

    // MLP head
    mlp_kernel<<<N_GRAPHS, 128, 0, stream>>>(
        gsum, gcnt, Wlin1, blin1, Wlin2, blin2, Wlin3, blin3,
        bng_g, bng_b, bng_m, bng_v, bn1_g, bn1_b, bn1_m, bn1_v,
        bn2_g, bn2_b, bn2_m, bn2_v, (float*)d_out);
}